// Round 11
// baseline (868.477 us; speedup 1.0000x reference)
//
#include <hip/hip_runtime.h>

typedef unsigned short u16;
typedef unsigned int   u32;
typedef __attribute__((ext_vector_type(4))) float f32x4;
using bf16x8 = __attribute__((ext_vector_type(8))) __bf16;

#define AS1 __attribute__((address_space(1)))
#define AS3 __attribute__((address_space(3)))

// ---------------- constants ----------------
#define SCALE_ 0.08838834764831845f   // 128^-0.5
// sizes: B=128, E=512, C=384, N=65 tokens, HD=128, H=3, MLP_H=1536, DEPTH=6

// ---------------- workspace layout (bytes) ----------------
#define X_OFF      0ull            // fp32 [8320][384]
#define Y_OFF      12779520ull     // bf16 [8320][384]
#define QKV_OFF    19169280ull     // bf16 [8320][1152]
#define OBAR_OFF   38338560ull     // bf16 [8320][384]
#define SCR_OFF    44728320ull     // union: im2col bf16 [8192][3072] / h1 bf16 [8320][1536]
#define PE_OFF     70287360ull     // bf16 [512][3][80][80]
#define WB_OFF     95059968ull     // all weights bf16
#define ELIST_OFF  118652928ull    // int [512]  (src, sorted by dst)
#define EOFF_OFF   118654976ull    // int [129]
#define INV_OFF    118655744ull    // float [128]
#define BSC_OFF    118656256ull    // float [128]
#define DLIST_OFF  118656768ull    // int [512]  (dst per sorted edge)

// weight element offsets inside WB (contiguous regions, in order)
#define PW_E   0
#define QW_E   1179648
#define PRW_E  3833856
#define F1W_E  4718592
#define F2W_E  8257536

// cvt_all region boundaries in float4 units
#define R0_ 294912
#define R1_ 958464
#define R2_ 1179648
#define R3_ 2064384
#define R4_ 2949120

// pv_k padded stride (elems)
#define PVS 104

// ---------------- helpers ----------------
__device__ __forceinline__ u16 f2bf(float f){
  union { float fv; u32 u; } x; x.fv = f;
  u32 r = x.u + 0x7FFFu + ((x.u >> 16) & 1u);
  return (u16)(r >> 16);
}
__device__ __forceinline__ float bf2f(u16 u){
  union { u32 u; float fv; } x; x.u = ((u32)u) << 16;
  return x.fv;
}
__device__ __forceinline__ void gld16(const void* g, void* l){
  __builtin_amdgcn_global_load_lds((AS1 void*)g, (AS3 void*)l, 16, 0, 0);
}

// ---------------- fp32 -> bf16 weight convert (all 5 tensors, one launch) ----------------
__global__ void cvt_all_k(const float* __restrict__ s0, const float* __restrict__ s1,
                          const float* __restrict__ s2, const float* __restrict__ s3,
                          const float* __restrict__ s4, u16* __restrict__ d){
  int i = blockIdx.x*256 + threadIdx.x;    // exactly R4_ threads
  const float* s; int rel;
  if (i < R0_)      { s = s0; rel = i; }
  else if (i < R1_) { s = s1; rel = i - R0_; }
  else if (i < R2_) { s = s2; rel = i - R1_; }
  else if (i < R3_) { s = s3; rel = i - R2_; }
  else              { s = s4; rel = i - R3_; }
  float4 v = ((const float4*)s)[rel];
  ushort4 o; o.x=f2bf(v.x); o.y=f2bf(v.y); o.z=f2bf(v.z); o.w=f2bf(v.w);
  ((ushort4*)d)[i] = o;
}

// ---------------- im2col: images[B,3,256,256] -> bf16 A[8192][3072], k=(c,kh,kw) ----------------
__global__ void im2col_k(const float* __restrict__ img, u16* __restrict__ A){
  int idx = blockIdx.x*256 + threadIdx.x;      // exactly 8192*384 threads
  int m = idx / 384, k8 = idx - m*384;
  int k = k8 * 8;
  int c  = k >> 10;
  int kh = (k >> 5) & 31;
  int kw = k & 31;                              // multiple of 8
  int b = m >> 6, p = m & 63;
  int ph = p >> 3, pw = p & 7;
  const float* src = img + ((size_t)(b*3 + c)*256 + ph*32 + kh)*256 + pw*32 + kw;
  float4 v0 = *(const float4*)src;
  float4 v1 = *(const float4*)(src + 4);
  uint4 ov; u16* tp = (u16*)&ov;
  tp[0]=f2bf(v0.x); tp[1]=f2bf(v0.y); tp[2]=f2bf(v0.z); tp[3]=f2bf(v0.w);
  tp[4]=f2bf(v1.x); tp[5]=f2bf(v1.y); tp[6]=f2bf(v1.z); tp[7]=f2bf(v1.w);
  *(uint4*)(A + (size_t)m*3072 + k) = ov;
}

// ---------------- cls token init: x[b][0][:] = cls + pos[0] ----------------
__global__ void cls_init_k(const float* __restrict__ cls, const float* __restrict__ pos,
                           float* __restrict__ X){
  int idx = blockIdx.x*256 + threadIdx.x;      // 128*384
  int b = idx / 384, c = idx - b*384;
  X[(size_t)b*65*384 + c] = cls[c] + pos[c];
}

// ---------------- edge bucketing (parallel, deterministic) ----------------
__global__ __launch_bounds__(128) void edge_prep_k(const int* __restrict__ ei,
                                                   int* __restrict__ elist,
                                                   int* __restrict__ eoff,
                                                   float* __restrict__ inv,
                                                   float* __restrict__ bsc,
                                                   int* __restrict__ dlist){
  __shared__ int srcS[512];
  __shared__ int dstS[512];
  __shared__ int cnt[128];
  const int t = threadIdx.x;   // 128 threads
  for (int e = t; e < 512; e += 128){ srcS[e] = ei[e]; dstS[e] = ei[512 + e]; }
  __syncthreads();
  int c = 0;
  for (int e = 0; e < 512; e++) c += (dstS[e] == t) ? 1 : 0;
  cnt[t] = c;
  __syncthreads();
  int off = 0;
  for (int b = 0; b < t; b++) off += cnt[b];
  eoff[t] = off;
  if (t == 127) eoff[128] = off + c;
  inv[t] = 1.0f / (float)(c > 1 ? c : 1);
  bsc[t] = (c > 0) ? 1.0f : 0.0f;
  int p = off;
  for (int e = 0; e < 512; e++){
    if (dstS[e] == t){ elist[p] = srcS[e]; dlist[p] = t; p++; }
  }
}

// ---------------- LayerNorm (fp32 in, bf16 out), 1 wave per row, float2-vectorized ----------------
__global__ __launch_bounds__(256) void ln_k(const float* __restrict__ X,
                                            const float* __restrict__ w,
                                            const float* __restrict__ b,
                                            u16* __restrict__ Y){
  int row  = blockIdx.x*4 + (threadIdx.x >> 6);
  int lane = threadIdx.x & 63;
  const float2* xr = (const float2*)(X + (size_t)row*384);
  const float2* wp = (const float2*)w;
  const float2* bp = (const float2*)b;
  float2 v[3]; float s = 0.f;
  #pragma unroll
  for (int i=0;i<3;i++){ v[i] = xr[lane + i*64]; s += v[i].x + v[i].y; }
  #pragma unroll
  for (int m=1;m<64;m<<=1) s += __shfl_xor(s, m);
  float mu = s * (1.f/384.f);
  float q = 0.f;
  #pragma unroll
  for (int i=0;i<3;i++){ float dx = v[i].x-mu, dy = v[i].y-mu; q += dx*dx + dy*dy; }
  #pragma unroll
  for (int m=1;m<64;m<<=1) q += __shfl_xor(q, m);
  float rs = rsqrtf(q*(1.f/384.f) + 1e-5f);
  ushort2* yr = (ushort2*)(Y + (size_t)row*384);
  #pragma unroll
  for (int i=0;i<3;i++){
    int e2 = lane + i*64;
    float2 wv = wp[e2], bv = bp[e2];
    ushort2 o;
    o.x = f2bf((v[i].x-mu)*rs*wv.x + bv.x);
    o.y = f2bf((v[i].y-mu)*rs*wv.y + bv.y);
    yr[e2] = o;
  }
}

// ---------------- final LN on cls rows -> fp32 out [128][384], float2-vectorized ----------------
__global__ __launch_bounds__(256) void ln_final_k(const float* __restrict__ X,
                                                  const float* __restrict__ w,
                                                  const float* __restrict__ b,
                                                  float* __restrict__ out){
  int bb   = blockIdx.x*4 + (threadIdx.x >> 6);   // 128 rows
  int lane = threadIdx.x & 63;
  const float2* xr = (const float2*)(X + (size_t)bb*65*384);
  const float2* wp = (const float2*)w;
  const float2* bp = (const float2*)b;
  float2 v[3]; float s = 0.f;
  #pragma unroll
  for (int i=0;i<3;i++){ v[i] = xr[lane + i*64]; s += v[i].x + v[i].y; }
  #pragma unroll
  for (int m=1;m<64;m<<=1) s += __shfl_xor(s, m);
  float mu = s * (1.f/384.f);
  float q = 0.f;
  #pragma unroll
  for (int i=0;i<3;i++){ float dx = v[i].x-mu, dy = v[i].y-mu; q += dx*dx + dy*dy; }
  #pragma unroll
  for (int m=1;m<64;m<<=1) q += __shfl_xor(q, m);
  float rs = rsqrtf(q*(1.f/384.f) + 1e-5f);
  float2* orow = (float2*)(out + (size_t)bb*384);
  #pragma unroll
  for (int i=0;i<3;i++){
    int e2 = lane + i*64;
    float2 wv = wp[e2], bv = bp[e2];
    float2 o;
    o.x = (v[i].x-mu)*rs*wv.x + bv.x;
    o.y = (v[i].y-mu)*rs*wv.y + bv.y;
    orow[e2] = o;
  }
}

// ---------------- NT-GEMM (R5-proven): BM=64 BN=128 BK=64, 2-buffer dbuf ----------------
// MODE 0 (qkv), MODE 1 (patch embed), MODE 3 (fc1) — grids >= 384 blocks.
template<int MODE>
__global__ __launch_bounds__(256) void gemm_nt(
    const u16* __restrict__ A, const u16* __restrict__ W, int K,
    u16* __restrict__ outb, float* __restrict__ outf,
    const float* __restrict__ bias, const float* __restrict__ extra, int ldout)
{
  __shared__ u16 As[2][4096];   // [2][64][64]
  __shared__ u16 Bs[2][8192];   // [2][128][64]
  const int t    = threadIdx.x;
  const int lane = t & 63;
  const int w    = t >> 6;
  const int wr   = w >> 1, wc = w & 1;
  const int m0 = blockIdx.x * 64, n0 = blockIdx.y * 128;
  const int rs = t >> 3;
  const int cs = (((t & 7) ^ (rs & 7))) * 8;   // swizzled source col
  const u16* Ag = A + (size_t)(m0 + rs) * K + cs;
  const u16* Wg = W + (size_t)(n0 + rs) * K + cs;
  const size_t K32 = (size_t)K * 32;
  const int ln15 = lane & 15, l8 = (lane >> 4) * 8, lq = (lane >> 4) << 2;
  const int swz = (ln15 & 7) << 3;             // read-side col XOR

  f32x4 acc[2][4] = {};
  const int nk = K >> 6;
  int cur = 0;

  gld16(Ag,           &As[0][t*8]);
  gld16(Ag + K32,     &As[0][2048 + t*8]);
  gld16(Wg,           &Bs[0][t*8]);
  gld16(Wg + K32,     &Bs[0][2048 + t*8]);
  gld16(Wg + 2*K32,   &Bs[0][4096 + t*8]);
  gld16(Wg + 3*K32,   &Bs[0][6144 + t*8]);
  __syncthreads();

  for (int kt = 1; kt <= nk; kt++){
    if (kt < nk){
      const int k0 = kt << 6;
      const int nb = cur ^ 1;
      gld16(Ag + k0,         &As[nb][t*8]);
      gld16(Ag + K32 + k0,   &As[nb][2048 + t*8]);
      gld16(Wg + k0,         &Bs[nb][t*8]);
      gld16(Wg + K32 + k0,   &Bs[nb][2048 + t*8]);
      gld16(Wg + 2*K32 + k0, &Bs[nb][4096 + t*8]);
      gld16(Wg + 3*K32 + k0, &Bs[nb][6144 + t*8]);
    }
    #pragma unroll
    for (int ks = 0; ks < 2; ks++){
      const int col = (ks*32 + l8) ^ swz;
      bf16x8 af[2], bfr[4];
      #pragma unroll
      for (int mi=0; mi<2; mi++)
        af[mi] = *(const bf16x8*)(&As[cur][(wr*32 + mi*16 + ln15)*64 + col]);
      #pragma unroll
      for (int ni=0; ni<4; ni++)
        bfr[ni] = *(const bf16x8*)(&Bs[cur][(wc*64 + ni*16 + ln15)*64 + col]);
      #pragma unroll
      for (int mi=0; mi<2; mi++)
        #pragma unroll
        for (int ni=0; ni<4; ni++)
          acc[mi][ni] = __builtin_amdgcn_mfma_f32_16x16x32_bf16(af[mi], bfr[ni], acc[mi][ni], 0,0,0);
    }
    if (kt < nk) __syncthreads();
    cur ^= 1;
  }

  #pragma unroll
  for (int mi=0; mi<2; mi++){
    #pragma unroll
    for (int j=0; j<4; j++){
      const int m = m0 + wr*32 + mi*16 + lq + j;
      #pragma unroll
      for (int ni=0; ni<4; ni++){
        const int n = n0 + wc*64 + ni*16 + ln15;
        float v = acc[mi][ni][j];
        if constexpr (MODE == 0){
          outb[(size_t)m*ldout + n] = f2bf(v);
        } else if constexpr (MODE == 1){
          int bb = m >> 6, p = m & 63;
          outf[((size_t)bb*65 + 1 + p)*384 + n] = v + bias[n] + extra[(1+p)*384 + n];
        } else if constexpr (MODE == 3){
          float g = v + bias[n];
          g = 0.5f*g*(1.f + erff(g*0.70710678118f));
          outb[(size_t)m*ldout + n] = f2bf(g);
        }
      }
    }
  }
}

// ---------------- NT-GEMM BN=64 variant: BM=64 BN=64 BK=64, 2-buffer dbuf ----------------
// For small-grid GEMMs (proj/fc2): doubles block count -> ~3 blocks/CU resident
// (grid was the binding constraint, not LDS). 32KB LDS, 2x2 frags/wave.
// MODE 2: proj residual  MODE 4: fc2 residual
template<int MODE>
__global__ __launch_bounds__(256) void gemm_nt64(
    const u16* __restrict__ A, const u16* __restrict__ W, int K,
    float* __restrict__ outf, const float* __restrict__ bias,
    const float* __restrict__ extra)
{
  __shared__ u16 As[2][4096];   // [2][64][64]
  __shared__ u16 Bs[2][4096];   // [2][64][64]
  const int t    = threadIdx.x;
  const int lane = t & 63;
  const int w    = t >> 6;
  const int wr   = w >> 1, wc = w & 1;
  const int m0 = blockIdx.x * 64, n0 = blockIdx.y * 64;
  const int rs = t >> 3;
  const int cs = (((t & 7) ^ (rs & 7))) * 8;   // swizzled source col
  const u16* Ag = A + (size_t)(m0 + rs) * K + cs;
  const u16* Wg = W + (size_t)(n0 + rs) * K + cs;
  const size_t K32 = (size_t)K * 32;
  const int ln15 = lane & 15, l8 = (lane >> 4) * 8, lq = (lane >> 4) << 2;
  const int swz = (ln15 & 7) << 3;             // read-side col XOR

  f32x4 acc[2][2] = {};
  const int nk = K >> 6;
  int cur = 0;

  gld16(Ag,       &As[0][t*8]);
  gld16(Ag + K32, &As[0][2048 + t*8]);
  gld16(Wg,       &Bs[0][t*8]);
  gld16(Wg + K32, &Bs[0][2048 + t*8]);
  __syncthreads();

  for (int kt = 1; kt <= nk; kt++){
    if (kt < nk){
      const int k0 = kt << 6;
      const int nb = cur ^ 1;
      gld16(Ag + k0,       &As[nb][t*8]);
      gld16(Ag + K32 + k0, &As[nb][2048 + t*8]);
      gld16(Wg + k0,       &Bs[nb][t*8]);
      gld16(Wg + K32 + k0, &Bs[nb][2048 + t*8]);
    }
    #pragma unroll
    for (int ks = 0; ks < 2; ks++){
      const int col = (ks*32 + l8) ^ swz;
      bf16x8 af[2], bfr[2];
      #pragma unroll
      for (int mi=0; mi<2; mi++)
        af[mi] = *(const bf16x8*)(&As[cur][(wr*32 + mi*16 + ln15)*64 + col]);
      #pragma unroll
      for (int ni=0; ni<2; ni++)
        bfr[ni] = *(const bf16x8*)(&Bs[cur][(wc*32 + ni*16 + ln15)*64 + col]);
      #pragma unroll
      for (int mi=0; mi<2; mi++)
        #pragma unroll
        for (int ni=0; ni<2; ni++)
          acc[mi][ni] = __builtin_amdgcn_mfma_f32_16x16x32_bf16(af[mi], bfr[ni], acc[mi][ni], 0,0,0);
    }
    if (kt < nk) __syncthreads();
    cur ^= 1;
  }

  #pragma unroll
  for (int mi=0; mi<2; mi++){
    #pragma unroll
    for (int j=0; j<4; j++){
      const int m = m0 + wr*32 + mi*16 + lq + j;
      #pragma unroll
      for (int ni=0; ni<2; ni++){
        const int n = n0 + wc*32 + ni*16 + ln15;
        float v = acc[mi][ni][j];
        if constexpr (MODE == 2){
          outf[(size_t)m*384 + n] += v + extra[m/65]*bias[n];
        } else {
          outf[(size_t)m*384 + n] += v + bias[n];
        }
      }
    }
  }
}

// ---------------- per-(edge,head) QK^T + softmax -> Pe bf16 [512][3][80][80] ----------------
__global__ __launch_bounds__(320) void qk_k(
    const u16* __restrict__ qkv, u16* __restrict__ Pe,
    const int* __restrict__ elist, const int* __restrict__ dlist)
{
  __shared__ u16 Qs[80*128];
  __shared__ u16 Ks[80*128];
  const int ee = blockIdx.x, h = blockIdx.y;
  const int t = threadIdx.x, w = t >> 6, lane = t & 63;
  const int ln15 = lane & 15, lq = (lane >> 4) << 2, l8 = (lane >> 4) * 8;
  const int b = dlist[ee], s = elist[ee];
  const size_t qbase = (size_t)b*65*1152 + h*128;
  const size_t kbase = (size_t)s*65*1152 + 384 + h*128;

  for (int idx = t; idx < 1040; idx += 320){
    int n = idx >> 4, g = idx & 15;
    int cc = (g ^ (n & 15)) * 8;               // swizzled source col
    gld16(qkv + qbase + (size_t)n*1152 + cc, Qs + idx*8);
    gld16(qkv + kbase + (size_t)n*1152 + cc, Ks + idx*8);
  }
  __syncthreads();

  const int swz = ln15 << 3;
  u16* pe = Pe + ((size_t)ee*3 + h)*6400;
  {
    const int rt = w;   // one row-tile per wave
    f32x4 sc[5] = {};
    #pragma unroll
    for (int ks=0; ks<4; ks++){
      const int col = (ks*32 + l8) ^ swz;
      bf16x8 a = *(const bf16x8*)(Qs + (rt*16 + ln15)*128 + col);
      #pragma unroll
      for (int ct=0; ct<5; ct++){
        bf16x8 kb = *(const bf16x8*)(Ks + (ct*16 + ln15)*128 + col);
        sc[ct] = __builtin_amdgcn_mfma_f32_16x16x32_bf16(a, kb, sc[ct], 0,0,0);
      }
    }
    #pragma unroll
    for (int j=0;j<4;j++){
      const int r = rt*16 + lq + j;
      const bool c4ok = (ln15 == 0);
      float ev[5];
      float mx = -1e30f;
      #pragma unroll
      for (int ct=0; ct<5; ct++){
        float sv = sc[ct][j] * SCALE_;
        ev[ct] = sv;
        if (ct < 4 || c4ok) mx = fmaxf(mx, sv);
      }
      #pragma unroll
      for (int mm=1; mm<16; mm<<=1) mx = fmaxf(mx, __shfl_xor(mx, mm));
      float se = 0.f;
      #pragma unroll
      for (int ct=0; ct<5; ct++){
        ev[ct] = (ct < 4 || c4ok) ? expf(ev[ct]-mx) : 0.f;
        se += ev[ct];
      }
      #pragma unroll
      for (int mm=1; mm<16; mm<<=1) se += __shfl_xor(se, mm);
      const float pscale = 1.f / se;
      if (r < 65){
        #pragma unroll
        for (int ct=0; ct<5; ct++)
          pe[r*80 + ct*16 + ln15] = f2bf(ev[ct]*pscale);
      }
    }
  }
}

// ---------------- per-(dst,head) combine + PV ----------------
__global__ __launch_bounds__(256) void pv_k(
    const u16* __restrict__ qkv, const u16* __restrict__ Pe,
    u16* __restrict__ obar, const int* __restrict__ eoff,
    const float* __restrict__ invc)
{
  __shared__ u16 Pb[80*PVS];
  __shared__ u16 Vt[128*PVS];
  const int b = blockIdx.x, h = blockIdx.y;
  const int t = threadIdx.x, w = t >> 6, lane = t & 63;
  const int ln15 = lane & 15, lq = (lane >> 4) << 2, l8 = (lane >> 4) * 8;
  const int e0 = eoff[b], e1 = eoff[b+1];
  const float inv = invc[b];

  float acc[25];
  #pragma unroll
  for (int i=0;i<25;i++) acc[i] = 0.f;
  for (int ee = e0; ee < e1; ee++){
    const u16* pe = Pe + ((size_t)ee*3 + h)*6400;
    #pragma unroll
    for (int i=0;i<25;i++) acc[i] += bf2f(pe[t + i*256]);
  }
  #pragma unroll
  for (int i=0;i<25;i++){
    int idx = t + i*256; int r = idx/80, c = idx - r*80;
    Pb[r*PVS + c] = f2bf(acc[i]*inv);
  }
  for (int idx = t; idx < 80*16; idx += 256)
    Pb[(idx>>4)*PVS + 80 + (idx & 15)] = 0;
  for (int idx = t; idx < 128*31; idx += 256){
    int d = idx / 31, m = 65 + (idx - d*31);
    Vt[d*PVS + m] = 0;
  }
  const size_t vbase = (size_t)b*65*1152 + 768 + h*128;
  for (int idx = t; idx < 1040; idx += 256){
    int m = idx >> 4, dc = (idx & 15)*8;
    uint4 v = *(const uint4*)(qkv + vbase + (size_t)m*1152 + dc);
    const u16* p = (const u16*)&v;
    #pragma unroll
    for (int i=0;i<8;i++) Vt[(dc+i)*PVS + m] = p[i];
  }
  __syncthreads();

  for (int ntile = w*2; ntile < w*2+2; ntile++){
    #pragma unroll
    for (int mt=0; mt<5; mt++){
      f32x4 oc = {};
      #pragma unroll
      for (int ks=0; ks<3; ks++){
        bf16x8 a  = *(const bf16x8*)(Pb + (mt*16 + ln15)*PVS + ks*32 + l8);
        bf16x8 vb = *(const bf16x8*)(Vt + (ntile*16 + ln15)*PVS + ks*32 + l8);
        oc = __builtin_amdgcn_mfma_f32_16x16x32_bf16(a, vb, oc, 0,0,0);
      }
      #pragma unroll
      for (int j=0;j<4;j++){
        int n = mt*16 + lq + j;
        if (n < 65) obar[((size_t)b*65 + n)*384 + h*128 + ntile*16 + ln15] = f2bf(oc[j]);
      }
    }
  }
}

// ---------------- launch ----------------
extern "C" void kernel_launch(void* const* d_in, const int* in_sizes, int n_in,
                              void* d_out, int out_size, void* d_ws, size_t ws_size,
                              hipStream_t stream) {
  (void)in_sizes; (void)n_in; (void)out_size; (void)ws_size;
  const float* images  = (const float*)d_in[0];
  const float* patch_w = (const float*)d_in[1];
  const float* patch_b = (const float*)d_in[2];
  const float* cls_tok = (const float*)d_in[3];
  const float* pos_emb = (const float*)d_in[4];
  const float* n1w = (const float*)d_in[5];
  const float* n1b = (const float*)d_in[6];
  const float* qkvw = (const float*)d_in[7];
  const float* projw = (const float*)d_in[8];
  const float* projb = (const float*)d_in[9];
  const float* n2w = (const float*)d_in[10];
  const float* n2b = (const float*)d_in[11];
  const float* f1w = (const float*)d_in[12];
  const float* f1b = (const float*)d_in[13];
  const float* f2w = (const float*)d_in[14];
  const float* f2b = (const float*)d_in[15];
  const float* nw  = (const float*)d_in[16];
  const float* nb  = (const float*)d_in[17];
  const int*   eidx = (const int*)d_in[18];

  char* ws = (char*)d_ws;
  float* X   = (float*)(ws + X_OFF);
  u16*   Y   = (u16*)(ws + Y_OFF);
  u16*   QKV = (u16*)(ws + QKV_OFF);
  u16*   OB  = (u16*)(ws + OBAR_OFF);
  u16*   SCR = (u16*)(ws + SCR_OFF);
  u16*   PE  = (u16*)(ws + PE_OFF);
  u16*   WB  = (u16*)(ws + WB_OFF);
  int*   ELIST = (int*)(ws + ELIST_OFF);
  int*   EOFF  = (int*)(ws + EOFF_OFF);
  float* INV   = (float*)(ws + INV_OFF);
  float* BSC   = (float*)(ws + BSC_OFF);
  int*   DLIST = (int*)(ws + DLIST_OFF);

  // weights -> bf16 (single launch)
  cvt_all_k<<<11520, 256, 0, stream>>>(patch_w, qkvw, projw, f1w, f2w, WB);

  edge_prep_k<<<1, 128, 0, stream>>>(eidx, ELIST, EOFF, INV, BSC, DLIST);
  im2col_k<<<12288, 256, 0, stream>>>(images, SCR);
  cls_init_k<<<192, 256, 0, stream>>>(cls_tok, pos_emb, X);

  // patch embed GEMM: [8192,3072] x [384,3072]^T -> x tokens 1..64 (+bias+pos)
  // BN=128 (grid 384 >= 256): halves re-reads of the 50MB im2col A vs BN=64.
  gemm_nt<1><<<dim3(128, 3), 256, 0, stream>>>(SCR, WB + PW_E, 3072,
                                               nullptr, X, patch_b, pos_emb, 0);

  for (int d = 0; d < 6; d++){
    ln_k<<<2080, 256, 0, stream>>>(X, n1w + d*384, n1b + d*384, Y);
    gemm_nt<0><<<dim3(130, 9), 256, 0, stream>>>(Y, WB + QW_E + (size_t)d*1152*384, 384,
                                                 QKV, nullptr, nullptr, nullptr, 1152);
    qk_k<<<dim3(512, 3), 320, 0, stream>>>(QKV, PE, ELIST, DLIST);
    pv_k<<<dim3(128, 3), 256, 0, stream>>>(QKV, PE, OB, EOFF, INV);
    gemm_nt64<2><<<dim3(130, 6), 256, 0, stream>>>(OB, WB + PRW_E + (size_t)d*384*384, 384,
                                                   X, projb + d*384, BSC);
    ln_k<<<2080, 256, 0, stream>>>(X, n2w + d*384, n2b + d*384, Y);
    gemm_nt<3><<<dim3(130, 12), 256, 0, stream>>>(Y, WB + F1W_E + (size_t)d*1536*384, 384,
                                                  SCR, nullptr, f1b + d*1536, nullptr, 1536);
    gemm_nt64<4><<<dim3(130, 6), 256, 0, stream>>>(SCR, WB + F2W_E + (size_t)d*384*1536, 1536,
                                                   X, f2b + d*384, nullptr);
  }

  ln_final_k<<<32, 256, 0, stream>>>(X, nw, nb, (float*)d_out);
}

// Round 12
// 859.302 us; speedup vs baseline: 1.0107x; 1.0107x over previous
//
#include <hip/hip_runtime.h>

typedef unsigned short u16;
typedef unsigned int   u32;
typedef __attribute__((ext_vector_type(4))) float f32x4;
using bf16x8 = __attribute__((ext_vector_type(8))) __bf16;

#define AS1 __attribute__((address_space(1)))
#define AS3 __attribute__((address_space(3)))

// ---------------- constants ----------------
#define SCALE_ 0.08838834764831845f   // 128^-0.5
// sizes: B=128, E=512, C=384, N=65 tokens, HD=128, H=3, MLP_H=1536, DEPTH=6

// ---------------- workspace layout (bytes) ----------------
#define X_OFF      0ull            // fp32 [8320][384]
#define Y_OFF      12779520ull     // bf16 [8320][384]
#define QKV_OFF    19169280ull     // bf16 [8320][1152]
#define OBAR_OFF   38338560ull     // bf16 [8320][384]
#define SCR_OFF    44728320ull     // union: im2col bf16 [8192][3072] / h1 bf16 [8320][1536]
#define PE_OFF     70287360ull     // bf16 [512][3][80][80]
#define WB_OFF     95059968ull     // all weights bf16
#define ELIST_OFF  118652928ull    // int [512]  (src, sorted by dst)
#define EOFF_OFF   118654976ull    // int [129]
#define INV_OFF    118655744ull    // float [128]
#define BSC_OFF    118656256ull    // float [128]
#define DLIST_OFF  118656768ull    // int [512]  (dst per sorted edge)

// weight element offsets inside WB (contiguous regions, in order)
#define PW_E   0
#define QW_E   1179648
#define PRW_E  3833856
#define F1W_E  4718592
#define F2W_E  8257536

// cvt region boundaries in float4 units
#define R0_ 294912
#define R1_ 958464
#define R2_ 1179648
#define R3_ 2064384
#define R4_ 2949120

// pre_k block-range boundaries
#define PB_CVT   11520
#define PB_IM    23808   // + 12288
#define PB_CLS   24000   // + 192
#define PB_TOT   24001   // + 1 edge_prep

// pv_k padded stride (elems); 208B row stride (16B-aligned: 208=16*13)
#define PVS 104

// ---------------- helpers ----------------
__device__ __forceinline__ u16 f2bf(float f){
  union { float fv; u32 u; } x; x.fv = f;
  u32 r = x.u + 0x7FFFu + ((x.u >> 16) & 1u);
  return (u16)(r >> 16);
}
__device__ __forceinline__ float bf2f(u16 u){
  union { u32 u; float fv; } x; x.u = ((u32)u) << 16;
  return x.fv;
}
__device__ __forceinline__ void gld16(const void* g, void* l){
  __builtin_amdgcn_global_load_lds((AS1 void*)g, (AS3 void*)l, 16, 0, 0);
}

// ---------------- merged preamble: cvt(5 tensors) | im2col | cls_init | edge_prep ----------------
__global__ __launch_bounds__(256) void pre_k(
    const float* __restrict__ patch_w, const float* __restrict__ qkvw,
    const float* __restrict__ projw, const float* __restrict__ f1w,
    const float* __restrict__ f2w, u16* __restrict__ WB,
    const float* __restrict__ img, u16* __restrict__ A,
    const float* __restrict__ cls, const float* __restrict__ pos, float* __restrict__ X,
    const int* __restrict__ ei, int* __restrict__ elist, int* __restrict__ eoff,
    float* __restrict__ inv, float* __restrict__ bsc, int* __restrict__ dlist)
{
  __shared__ int srcS[512];
  __shared__ int dstS[512];
  __shared__ int cnt[128];
  const int bx = blockIdx.x, t = threadIdx.x;

  if (bx < PB_CVT){
    // fp32 -> bf16 weight convert
    int i = bx*256 + t;
    const float* s; int rel;
    if (i < R0_)      { s = patch_w; rel = i; }
    else if (i < R1_) { s = qkvw;    rel = i - R0_; }
    else if (i < R2_) { s = projw;   rel = i - R1_; }
    else if (i < R3_) { s = f1w;     rel = i - R2_; }
    else              { s = f2w;     rel = i - R3_; }
    float4 v = ((const float4*)s)[rel];
    ushort4 o; o.x=f2bf(v.x); o.y=f2bf(v.y); o.z=f2bf(v.z); o.w=f2bf(v.w);
    ((ushort4*)WB)[i] = o;
  } else if (bx < PB_IM){
    // im2col: images[B,3,256,256] -> bf16 A[8192][3072], k=(c,kh,kw)
    int idx = (bx - PB_CVT)*256 + t;
    int m = idx / 384, k8 = idx - m*384;
    int k = k8 * 8;
    int c  = k >> 10;
    int kh = (k >> 5) & 31;
    int kw = k & 31;
    int b = m >> 6, p = m & 63;
    int ph = p >> 3, pw = p & 7;
    const float* src = img + ((size_t)(b*3 + c)*256 + ph*32 + kh)*256 + pw*32 + kw;
    float4 v0 = *(const float4*)src;
    float4 v1 = *(const float4*)(src + 4);
    uint4 ov; u16* tp = (u16*)&ov;
    tp[0]=f2bf(v0.x); tp[1]=f2bf(v0.y); tp[2]=f2bf(v0.z); tp[3]=f2bf(v0.w);
    tp[4]=f2bf(v1.x); tp[5]=f2bf(v1.y); tp[6]=f2bf(v1.z); tp[7]=f2bf(v1.w);
    *(uint4*)(A + (size_t)m*3072 + k) = ov;
  } else if (bx < PB_CLS){
    // cls token init
    int idx = (bx - PB_IM)*256 + t;
    int b = idx / 384, c = idx - b*384;
    X[(size_t)b*65*384 + c] = cls[c] + pos[c];
  } else {
    // edge bucketing (deterministic); all 256 threads reach barriers
    for (int e = t; e < 512; e += 256){ srcS[e] = ei[e]; dstS[e] = ei[512 + e]; }
    __syncthreads();
    if (t < 128){
      int c = 0;
      for (int e = 0; e < 512; e++) c += (dstS[e] == t) ? 1 : 0;
      cnt[t] = c;
    }
    __syncthreads();
    if (t < 128){
      int c = cnt[t];
      int off = 0;
      for (int b = 0; b < t; b++) off += cnt[b];
      eoff[t] = off;
      if (t == 127) eoff[128] = off + c;
      inv[t] = 1.0f / (float)(c > 1 ? c : 1);
      bsc[t] = (c > 0) ? 1.0f : 0.0f;
      int p = off;
      for (int e = 0; e < 512; e++){
        if (dstS[e] == t){ elist[p] = srcS[e]; dlist[p] = t; p++; }
      }
    }
  }
}

// ---------------- LayerNorm (fp32 in, bf16 out), 1 wave per row, float2-vectorized ----------------
__global__ __launch_bounds__(256) void ln_k(const float* __restrict__ X,
                                            const float* __restrict__ w,
                                            const float* __restrict__ b,
                                            u16* __restrict__ Y){
  int row  = blockIdx.x*4 + (threadIdx.x >> 6);
  int lane = threadIdx.x & 63;
  const float2* xr = (const float2*)(X + (size_t)row*384);
  const float2* wp = (const float2*)w;
  const float2* bp = (const float2*)b;
  float2 v[3]; float s = 0.f;
  #pragma unroll
  for (int i=0;i<3;i++){ v[i] = xr[lane + i*64]; s += v[i].x + v[i].y; }
  #pragma unroll
  for (int m=1;m<64;m<<=1) s += __shfl_xor(s, m);
  float mu = s * (1.f/384.f);
  float q = 0.f;
  #pragma unroll
  for (int i=0;i<3;i++){ float dx = v[i].x-mu, dy = v[i].y-mu; q += dx*dx + dy*dy; }
  #pragma unroll
  for (int m=1;m<64;m<<=1) q += __shfl_xor(q, m);
  float rs = rsqrtf(q*(1.f/384.f) + 1e-5f);
  ushort2* yr = (ushort2*)(Y + (size_t)row*384);
  #pragma unroll
  for (int i=0;i<3;i++){
    int e2 = lane + i*64;
    float2 wv = wp[e2], bv = bp[e2];
    ushort2 o;
    o.x = f2bf((v[i].x-mu)*rs*wv.x + bv.x);
    o.y = f2bf((v[i].y-mu)*rs*wv.y + bv.y);
    yr[e2] = o;
  }
}

// ---------------- final LN on cls rows -> fp32 out [128][384], float2-vectorized ----------------
__global__ __launch_bounds__(256) void ln_final_k(const float* __restrict__ X,
                                                  const float* __restrict__ w,
                                                  const float* __restrict__ b,
                                                  float* __restrict__ out){
  int bb   = blockIdx.x*4 + (threadIdx.x >> 6);   // 128 rows
  int lane = threadIdx.x & 63;
  const float2* xr = (const float2*)(X + (size_t)bb*65*384);
  const float2* wp = (const float2*)w;
  const float2* bp = (const float2*)b;
  float2 v[3]; float s = 0.f;
  #pragma unroll
  for (int i=0;i<3;i++){ v[i] = xr[lane + i*64]; s += v[i].x + v[i].y; }
  #pragma unroll
  for (int m=1;m<64;m<<=1) s += __shfl_xor(s, m);
  float mu = s * (1.f/384.f);
  float q = 0.f;
  #pragma unroll
  for (int i=0;i<3;i++){ float dx = v[i].x-mu, dy = v[i].y-mu; q += dx*dx + dy*dy; }
  #pragma unroll
  for (int m=1;m<64;m<<=1) q += __shfl_xor(q, m);
  float rs = rsqrtf(q*(1.f/384.f) + 1e-5f);
  float2* orow = (float2*)(out + (size_t)bb*384);
  #pragma unroll
  for (int i=0;i<3;i++){
    int e2 = lane + i*64;
    float2 wv = wp[e2], bv = bp[e2];
    float2 o;
    o.x = (v[i].x-mu)*rs*wv.x + bv.x;
    o.y = (v[i].y-mu)*rs*wv.y + bv.y;
    orow[e2] = o;
  }
}

// ---------------- NT-GEMM (R5-proven): BM=64 BN=128 BK=64, 2-buffer dbuf ----------------
// MODE 0 (qkv), MODE 1 (patch embed), MODE 3 (fc1) — grids >= 384 blocks.
template<int MODE>
__global__ __launch_bounds__(256) void gemm_nt(
    const u16* __restrict__ A, const u16* __restrict__ W, int K,
    u16* __restrict__ outb, float* __restrict__ outf,
    const float* __restrict__ bias, const float* __restrict__ extra, int ldout)
{
  __shared__ u16 As[2][4096];   // [2][64][64]
  __shared__ u16 Bs[2][8192];   // [2][128][64]
  const int t    = threadIdx.x;
  const int lane = t & 63;
  const int w    = t >> 6;
  const int wr   = w >> 1, wc = w & 1;
  const int m0 = blockIdx.x * 64, n0 = blockIdx.y * 128;
  const int rs = t >> 3;
  const int cs = (((t & 7) ^ (rs & 7))) * 8;   // swizzled source col
  const u16* Ag = A + (size_t)(m0 + rs) * K + cs;
  const u16* Wg = W + (size_t)(n0 + rs) * K + cs;
  const size_t K32 = (size_t)K * 32;
  const int ln15 = lane & 15, l8 = (lane >> 4) * 8, lq = (lane >> 4) << 2;
  const int swz = (ln15 & 7) << 3;             // read-side col XOR

  f32x4 acc[2][4] = {};
  const int nk = K >> 6;
  int cur = 0;

  gld16(Ag,           &As[0][t*8]);
  gld16(Ag + K32,     &As[0][2048 + t*8]);
  gld16(Wg,           &Bs[0][t*8]);
  gld16(Wg + K32,     &Bs[0][2048 + t*8]);
  gld16(Wg + 2*K32,   &Bs[0][4096 + t*8]);
  gld16(Wg + 3*K32,   &Bs[0][6144 + t*8]);
  __syncthreads();

  for (int kt = 1; kt <= nk; kt++){
    if (kt < nk){
      const int k0 = kt << 6;
      const int nb = cur ^ 1;
      gld16(Ag + k0,         &As[nb][t*8]);
      gld16(Ag + K32 + k0,   &As[nb][2048 + t*8]);
      gld16(Wg + k0,         &Bs[nb][t*8]);
      gld16(Wg + K32 + k0,   &Bs[nb][2048 + t*8]);
      gld16(Wg + 2*K32 + k0, &Bs[nb][4096 + t*8]);
      gld16(Wg + 3*K32 + k0, &Bs[nb][6144 + t*8]);
    }
    #pragma unroll
    for (int ks = 0; ks < 2; ks++){
      const int col = (ks*32 + l8) ^ swz;
      bf16x8 af[2], bfr[4];
      #pragma unroll
      for (int mi=0; mi<2; mi++)
        af[mi] = *(const bf16x8*)(&As[cur][(wr*32 + mi*16 + ln15)*64 + col]);
      #pragma unroll
      for (int ni=0; ni<4; ni++)
        bfr[ni] = *(const bf16x8*)(&Bs[cur][(wc*64 + ni*16 + ln15)*64 + col]);
      #pragma unroll
      for (int mi=0; mi<2; mi++)
        #pragma unroll
        for (int ni=0; ni<4; ni++)
          acc[mi][ni] = __builtin_amdgcn_mfma_f32_16x16x32_bf16(af[mi], bfr[ni], acc[mi][ni], 0,0,0);
    }
    if (kt < nk) __syncthreads();
    cur ^= 1;
  }

  #pragma unroll
  for (int mi=0; mi<2; mi++){
    #pragma unroll
    for (int j=0; j<4; j++){
      const int m = m0 + wr*32 + mi*16 + lq + j;
      #pragma unroll
      for (int ni=0; ni<4; ni++){
        const int n = n0 + wc*64 + ni*16 + ln15;
        float v = acc[mi][ni][j];
        if constexpr (MODE == 0){
          outb[(size_t)m*ldout + n] = f2bf(v);
        } else if constexpr (MODE == 1){
          int bb = m >> 6, p = m & 63;
          outf[((size_t)bb*65 + 1 + p)*384 + n] = v + bias[n] + extra[(1+p)*384 + n];
        } else if constexpr (MODE == 3){
          float g = v + bias[n];
          g = 0.5f*g*(1.f + erff(g*0.70710678118f));
          outb[(size_t)m*ldout + n] = f2bf(g);
        }
      }
    }
  }
}

// ---------------- NT-GEMM BN=64 variant: BM=64 BN=64 BK=64, 2-buffer dbuf ----------------
// For small-grid GEMMs (proj/fc2): doubles block count -> ~3 blocks/CU resident.
// MODE 2: proj residual  MODE 4: fc2 residual
template<int MODE>
__global__ __launch_bounds__(256) void gemm_nt64(
    const u16* __restrict__ A, const u16* __restrict__ W, int K,
    float* __restrict__ outf, const float* __restrict__ bias,
    const float* __restrict__ extra)
{
  __shared__ u16 As[2][4096];   // [2][64][64]
  __shared__ u16 Bs[2][4096];   // [2][64][64]
  const int t    = threadIdx.x;
  const int lane = t & 63;
  const int w    = t >> 6;
  const int wr   = w >> 1, wc = w & 1;
  const int m0 = blockIdx.x * 64, n0 = blockIdx.y * 64;
  const int rs = t >> 3;
  const int cs = (((t & 7) ^ (rs & 7))) * 8;   // swizzled source col
  const u16* Ag = A + (size_t)(m0 + rs) * K + cs;
  const u16* Wg = W + (size_t)(n0 + rs) * K + cs;
  const size_t K32 = (size_t)K * 32;
  const int ln15 = lane & 15, l8 = (lane >> 4) * 8, lq = (lane >> 4) << 2;
  const int swz = (ln15 & 7) << 3;             // read-side col XOR

  f32x4 acc[2][2] = {};
  const int nk = K >> 6;
  int cur = 0;

  gld16(Ag,       &As[0][t*8]);
  gld16(Ag + K32, &As[0][2048 + t*8]);
  gld16(Wg,       &Bs[0][t*8]);
  gld16(Wg + K32, &Bs[0][2048 + t*8]);
  __syncthreads();

  for (int kt = 1; kt <= nk; kt++){
    if (kt < nk){
      const int k0 = kt << 6;
      const int nb = cur ^ 1;
      gld16(Ag + k0,       &As[nb][t*8]);
      gld16(Ag + K32 + k0, &As[nb][2048 + t*8]);
      gld16(Wg + k0,       &Bs[nb][t*8]);
      gld16(Wg + K32 + k0, &Bs[nb][2048 + t*8]);
    }
    #pragma unroll
    for (int ks = 0; ks < 2; ks++){
      const int col = (ks*32 + l8) ^ swz;
      bf16x8 af[2], bfr[2];
      #pragma unroll
      for (int mi=0; mi<2; mi++)
        af[mi] = *(const bf16x8*)(&As[cur][(wr*32 + mi*16 + ln15)*64 + col]);
      #pragma unroll
      for (int ni=0; ni<2; ni++)
        bfr[ni] = *(const bf16x8*)(&Bs[cur][(wc*32 + ni*16 + ln15)*64 + col]);
      #pragma unroll
      for (int mi=0; mi<2; mi++)
        #pragma unroll
        for (int ni=0; ni<2; ni++)
          acc[mi][ni] = __builtin_amdgcn_mfma_f32_16x16x32_bf16(af[mi], bfr[ni], acc[mi][ni], 0,0,0);
    }
    if (kt < nk) __syncthreads();
    cur ^= 1;
  }

  #pragma unroll
  for (int mi=0; mi<2; mi++){
    #pragma unroll
    for (int j=0; j<4; j++){
      const int m = m0 + wr*32 + mi*16 + lq + j;
      #pragma unroll
      for (int ni=0; ni<2; ni++){
        const int n = n0 + wc*32 + ni*16 + ln15;
        float v = acc[mi][ni][j];
        if constexpr (MODE == 2){
          outf[(size_t)m*384 + n] += v + extra[m/65]*bias[n];
        } else {
          outf[(size_t)m*384 + n] += v + bias[n];
        }
      }
    }
  }
}

// ---------------- per-(edge,head) QK^T + softmax -> Pe bf16 [512][3][80][80] ----------------
__global__ __launch_bounds__(320) void qk_k(
    const u16* __restrict__ qkv, u16* __restrict__ Pe,
    const int* __restrict__ elist, const int* __restrict__ dlist)
{
  __shared__ u16 Qs[80*128];
  __shared__ u16 Ks[80*128];
  const int ee = blockIdx.x, h = blockIdx.y;
  const int t = threadIdx.x, w = t >> 6, lane = t & 63;
  const int ln15 = lane & 15, lq = (lane >> 4) << 2, l8 = (lane >> 4) * 8;
  const int b = dlist[ee], s = elist[ee];
  const size_t qbase = (size_t)b*65*1152 + h*128;
  const size_t kbase = (size_t)s*65*1152 + 384 + h*128;

  for (int idx = t; idx < 1040; idx += 320){
    int n = idx >> 4, g = idx & 15;
    int cc = (g ^ (n & 15)) * 8;               // swizzled source col
    gld16(qkv + qbase + (size_t)n*1152 + cc, Qs + idx*8);
    gld16(qkv + kbase + (size_t)n*1152 + cc, Ks + idx*8);
  }
  __syncthreads();

  const int swz = ln15 << 3;
  u16* pe = Pe + ((size_t)ee*3 + h)*6400;
  {
    const int rt = w;   // one row-tile per wave
    f32x4 sc[5] = {};
    #pragma unroll
    for (int ks=0; ks<4; ks++){
      const int col = (ks*32 + l8) ^ swz;
      bf16x8 a = *(const bf16x8*)(Qs + (rt*16 + ln15)*128 + col);
      #pragma unroll
      for (int ct=0; ct<5; ct++){
        bf16x8 kb = *(const bf16x8*)(Ks + (ct*16 + ln15)*128 + col);
        sc[ct] = __builtin_amdgcn_mfma_f32_16x16x32_bf16(a, kb, sc[ct], 0,0,0);
      }
    }
    #pragma unroll
    for (int j=0;j<4;j++){
      const int r = rt*16 + lq + j;
      const bool c4ok = (ln15 == 0);
      float ev[5];
      float mx = -1e30f;
      #pragma unroll
      for (int ct=0; ct<5; ct++){
        float sv = sc[ct][j] * SCALE_;
        ev[ct] = sv;
        if (ct < 4 || c4ok) mx = fmaxf(mx, sv);
      }
      #pragma unroll
      for (int mm=1; mm<16; mm<<=1) mx = fmaxf(mx, __shfl_xor(mx, mm));
      float se = 0.f;
      #pragma unroll
      for (int ct=0; ct<5; ct++){
        ev[ct] = (ct < 4 || c4ok) ? expf(ev[ct]-mx) : 0.f;
        se += ev[ct];
      }
      #pragma unroll
      for (int mm=1; mm<16; mm<<=1) se += __shfl_xor(se, mm);
      const float pscale = 1.f / se;
      if (r < 65){
        #pragma unroll
        for (int ct=0; ct<5; ct++)
          pe[r*80 + ct*16 + ln15] = f2bf(ev[ct]*pscale);
      }
    }
  }
}

// ---------------- per-(dst,head) combine + PV ----------------
// Edge-gather vectorized: 6400 = 256*24 + 256; thread t owns uint4 chunks
// {t, t+256, t+512} (8 bf16 each; 80%8==0 so chunks never cross rows) plus
// scalar elem 6144+t. Same per-element accumulation order as before.
__global__ __launch_bounds__(256) void pv_k(
    const u16* __restrict__ qkv, const u16* __restrict__ Pe,
    u16* __restrict__ obar, const int* __restrict__ eoff,
    const float* __restrict__ invc)
{
  __shared__ u16 Pb[80*PVS];
  __shared__ u16 Vt[128*PVS];
  const int b = blockIdx.x, h = blockIdx.y;
  const int t = threadIdx.x, w = t >> 6, lane = t & 63;
  const int ln15 = lane & 15, lq = (lane >> 4) << 2, l8 = (lane >> 4) * 8;
  const int e0 = eoff[b], e1 = eoff[b+1];
  const float inv = invc[b];

  float a8[3][8];
  float asc = 0.f;
  #pragma unroll
  for (int i=0;i<3;i++)
    #pragma unroll
    for (int j=0;j<8;j++) a8[i][j] = 0.f;
  for (int ee = e0; ee < e1; ee++){
    const u16* pe = Pe + ((size_t)ee*3 + h)*6400;
    #pragma unroll
    for (int i=0;i<3;i++){
      uint4 v = *(const uint4*)(pe + (size_t)(t + i*256)*8);
      const u16* p = (const u16*)&v;
      #pragma unroll
      for (int j=0;j<8;j++) a8[i][j] += bf2f(p[j]);
    }
    asc += bf2f(pe[6144 + t]);
  }
  #pragma unroll
  for (int i=0;i<3;i++){
    int e = (t + i*256)*8;
    int r = e/80, c = e - r*80;
    uint4 ov; u16* op = (u16*)&ov;
    #pragma unroll
    for (int j=0;j<8;j++) op[j] = f2bf(a8[i][j]*inv);
    *(uint4*)(&Pb[r*PVS + c]) = ov;
  }
  {
    int e = 6144 + t;
    int r = e/80, c = e - r*80;
    Pb[r*PVS + c] = f2bf(asc*inv);
  }
  for (int idx = t; idx < 80*16; idx += 256)
    Pb[(idx>>4)*PVS + 80 + (idx & 15)] = 0;
  for (int idx = t; idx < 128*31; idx += 256){
    int d = idx / 31, m = 65 + (idx - d*31);
    Vt[d*PVS + m] = 0;
  }
  const size_t vbase = (size_t)b*65*1152 + 768 + h*128;
  for (int idx = t; idx < 1040; idx += 256){
    int m = idx >> 4, dc = (idx & 15)*8;
    uint4 v = *(const uint4*)(qkv + vbase + (size_t)m*1152 + dc);
    const u16* p = (const u16*)&v;
    #pragma unroll
    for (int i=0;i<8;i++) Vt[(dc+i)*PVS + m] = p[i];
  }
  __syncthreads();

  for (int ntile = w*2; ntile < w*2+2; ntile++){
    #pragma unroll
    for (int mt=0; mt<5; mt++){
      f32x4 oc = {};
      #pragma unroll
      for (int ks=0; ks<3; ks++){
        bf16x8 a  = *(const bf16x8*)(Pb + (mt*16 + ln15)*PVS + ks*32 + l8);
        bf16x8 vb = *(const bf16x8*)(Vt + (ntile*16 + ln15)*PVS + ks*32 + l8);
        oc = __builtin_amdgcn_mfma_f32_16x16x32_bf16(a, vb, oc, 0,0,0);
      }
      #pragma unroll
      for (int j=0;j<4;j++){
        int n = mt*16 + lq + j;
        if (n < 65) obar[((size_t)b*65 + n)*384 + h*128 + ntile*16 + ln15] = f2bf(oc[j]);
      }
    }
  }
}

// ---------------- launch ----------------
extern "C" void kernel_launch(void* const* d_in, const int* in_sizes, int n_in,
                              void* d_out, int out_size, void* d_ws, size_t ws_size,
                              hipStream_t stream) {
  (void)in_sizes; (void)n_in; (void)out_size; (void)ws_size;
  const float* images  = (const float*)d_in[0];
  const float* patch_w = (const float*)d_in[1];
  const float* patch_b = (const float*)d_in[2];
  const float* cls_tok = (const float*)d_in[3];
  const float* pos_emb = (const float*)d_in[4];
  const float* n1w = (const float*)d_in[5];
  const float* n1b = (const float*)d_in[6];
  const float* qkvw = (const float*)d_in[7];
  const float* projw = (const float*)d_in[8];
  const float* projb = (const float*)d_in[9];
  const float* n2w = (const float*)d_in[10];
  const float* n2b = (const float*)d_in[11];
  const float* f1w = (const float*)d_in[12];
  const float* f1b = (const float*)d_in[13];
  const float* f2w = (const float*)d_in[14];
  const float* f2b = (const float*)d_in[15];
  const float* nw  = (const float*)d_in[16];
  const float* nb  = (const float*)d_in[17];
  const int*   eidx = (const int*)d_in[18];

  char* ws = (char*)d_ws;
  float* X   = (float*)(ws + X_OFF);
  u16*   Y   = (u16*)(ws + Y_OFF);
  u16*   QKV = (u16*)(ws + QKV_OFF);
  u16*   OB  = (u16*)(ws + OBAR_OFF);
  u16*   SCR = (u16*)(ws + SCR_OFF);
  u16*   PE  = (u16*)(ws + PE_OFF);
  u16*   WB  = (u16*)(ws + WB_OFF);
  int*   ELIST = (int*)(ws + ELIST_OFF);
  int*   EOFF  = (int*)(ws + EOFF_OFF);
  float* INV   = (float*)(ws + INV_OFF);
  float* BSC   = (float*)(ws + BSC_OFF);
  int*   DLIST = (int*)(ws + DLIST_OFF);

  // merged preamble: weights->bf16 | im2col | cls_init | edge_prep (one dispatch)
  pre_k<<<PB_TOT, 256, 0, stream>>>(patch_w, qkvw, projw, f1w, f2w, WB,
                                    images, SCR,
                                    cls_tok, pos_emb, X,
                                    eidx, ELIST, EOFF, INV, BSC, DLIST);

  // patch embed GEMM: [8192,3072] x [384,3072]^T -> x tokens 1..64 (+bias+pos)
  gemm_nt<1><<<dim3(128, 3), 256, 0, stream>>>(SCR, WB + PW_E, 3072,
                                               nullptr, X, patch_b, pos_emb, 0);

  for (int d = 0; d < 6; d++){
    ln_k<<<2080, 256, 0, stream>>>(X, n1w + d*384, n1b + d*384, Y);
    gemm_nt<0><<<dim3(130, 9), 256, 0, stream>>>(Y, WB + QW_E + (size_t)d*1152*384, 384,
                                                 QKV, nullptr, nullptr, nullptr, 1152);
    qk_k<<<dim3(512, 3), 320, 0, stream>>>(QKV, PE, ELIST, DLIST);
    pv_k<<<dim3(128, 3), 256, 0, stream>>>(QKV, PE, OB, EOFF, INV);
    gemm_nt64<2><<<dim3(130, 6), 256, 0, stream>>>(OB, WB + PRW_E + (size_t)d*384*384, 384,
                                                   X, projb + d*384, BSC);
    ln_k<<<2080, 256, 0, stream>>>(X, n2w + d*384, n2b + d*384, Y);
    gemm_nt<3><<<dim3(130, 12), 256, 0, stream>>>(Y, WB + F1W_E + (size_t)d*1536*384, 384,
                                                  SCR, nullptr, f1b + d*1536, nullptr, 1536);
    gemm_nt64<4><<<dim3(130, 6), 256, 0, stream>>>(SCR, WB + F2W_E + (size_t)d*384*1536, 1536,
                                                   X, f2b + d*384, nullptr);
  }

  ln_final_k<<<32, 256, 0, stream>>>(X, nw, nb, (float*)d_out);
}

// Round 13
// 838.834 us; speedup vs baseline: 1.0353x; 1.0244x over previous
//
#include <hip/hip_runtime.h>

typedef unsigned short u16;
typedef unsigned int   u32;
typedef __attribute__((ext_vector_type(4))) float f32x4;
using bf16x8 = __attribute__((ext_vector_type(8))) __bf16;

#define AS1 __attribute__((address_space(1)))
#define AS3 __attribute__((address_space(3)))

// ---------------- constants ----------------
#define SCALE_ 0.08838834764831845f   // 128^-0.5
// sizes: B=128, E=512, C=384, N=65 tokens, HD=128, H=3, MLP_H=1536, DEPTH=6

// ---------------- workspace layout (bytes) ----------------
#define X_OFF      0ull            // fp32 [8320][384]
#define Y_OFF      12779520ull     // bf16 [8320][384]
#define QKV_OFF    19169280ull     // bf16 [8320][1152]
#define OBAR_OFF   38338560ull     // bf16 [8320][384]
#define SCR_OFF    44728320ull     // union: im2col bf16 [8192][3072] / h1 bf16 [8320][1536]
#define PE_OFF     70287360ull     // bf16 [512][3][80][80]
#define WB_OFF     95059968ull     // all weights bf16
#define ELIST_OFF  118652928ull    // int [512]  (src, sorted by dst)
#define EOFF_OFF   118654976ull    // int [129]
#define INV_OFF    118655744ull    // float [128]
#define BSC_OFF    118656256ull    // float [128]
#define DLIST_OFF  118656768ull    // int [512]  (dst per sorted edge)

// weight element offsets inside WB (contiguous regions, in order)
#define PW_E   0
#define QW_E   1179648
#define PRW_E  3833856
#define F1W_E  4718592
#define F2W_E  8257536

// cvt region boundaries in float4 units
#define R0_ 294912
#define R1_ 958464
#define R2_ 1179648
#define R3_ 2064384
#define R4_ 2949120

// pre_k block-range boundaries: edge_prep FIRST (serial block overlaps stream)
#define PB_EDGE  1
#define PB_CVT   11521   // + 11520 cvt
#define PB_IM    23809   // + 12288 im2col
#define PB_TOT   24001   // + 192 cls_init

// pv_k padded stride (elems); 208B row stride (16B-aligned: 208=16*13)
#define PVS 104

// ---------------- helpers ----------------
__device__ __forceinline__ u16 f2bf(float f){
  union { float fv; u32 u; } x; x.fv = f;
  u32 r = x.u + 0x7FFFu + ((x.u >> 16) & 1u);
  return (u16)(r >> 16);
}
__device__ __forceinline__ float bf2f(u16 u){
  union { u32 u; float fv; } x; x.u = ((u32)u) << 16;
  return x.fv;
}
__device__ __forceinline__ void gld16(const void* g, void* l){
  __builtin_amdgcn_global_load_lds((AS1 void*)g, (AS3 void*)l, 16, 0, 0);
}

// ---------------- merged preamble: edge_prep | cvt(5 tensors) | im2col | cls_init ----------------
// im2col mapping is IMAGE-ORDER: thread idx owns 8 consecutive floats of an
// image row -> wave reads 2KB fully contiguous (was 128B segs @ 1KB stride).
// Writes become 64B segments @ 6KB stride (half the byte volume; L2-buffered).
__global__ __launch_bounds__(256) void pre_k(
    const float* __restrict__ patch_w, const float* __restrict__ qkvw,
    const float* __restrict__ projw, const float* __restrict__ f1w,
    const float* __restrict__ f2w, u16* __restrict__ WB,
    const float* __restrict__ img, u16* __restrict__ A,
    const float* __restrict__ cls, const float* __restrict__ pos, float* __restrict__ X,
    const int* __restrict__ ei, int* __restrict__ elist, int* __restrict__ eoff,
    float* __restrict__ inv, float* __restrict__ bsc, int* __restrict__ dlist)
{
  __shared__ int srcS[512];
  __shared__ int dstS[512];
  __shared__ int cnt[128];
  const int bx = blockIdx.x, t = threadIdx.x;

  if (bx < PB_EDGE){
    // edge bucketing (deterministic); all 256 threads reach barriers
    for (int e = t; e < 512; e += 256){ srcS[e] = ei[e]; dstS[e] = ei[512 + e]; }
    __syncthreads();
    if (t < 128){
      int c = 0;
      for (int e = 0; e < 512; e++) c += (dstS[e] == t) ? 1 : 0;
      cnt[t] = c;
    }
    __syncthreads();
    if (t < 128){
      int c = cnt[t];
      int off = 0;
      for (int b = 0; b < t; b++) off += cnt[b];
      eoff[t] = off;
      if (t == 127) eoff[128] = off + c;
      inv[t] = 1.0f / (float)(c > 1 ? c : 1);
      bsc[t] = (c > 0) ? 1.0f : 0.0f;
      int p = off;
      for (int e = 0; e < 512; e++){
        if (dstS[e] == t){ elist[p] = srcS[e]; dlist[p] = t; p++; }
      }
    }
  } else if (bx < PB_CVT){
    // fp32 -> bf16 weight convert (fully coalesced both sides)
    int i = (bx - PB_EDGE)*256 + t;
    const float* s; int rel;
    if (i < R0_)      { s = patch_w; rel = i; }
    else if (i < R1_) { s = qkvw;    rel = i - R0_; }
    else if (i < R2_) { s = projw;   rel = i - R1_; }
    else if (i < R3_) { s = f1w;     rel = i - R2_; }
    else              { s = f2w;     rel = i - R3_; }
    float4 v = ((const float4*)s)[rel];
    ushort4 o; o.x=f2bf(v.x); o.y=f2bf(v.y); o.z=f2bf(v.z); o.w=f2bf(v.w);
    ((ushort4*)WB)[i] = o;
  } else if (bx < PB_IM){
    // im2col, image-order: idx = ((b*3+c)*256 + row)*32 + cb  (8 floats/thread)
    int idx = (bx - PB_CVT)*256 + t;        // [0, 128*3*256*32)
    int b    = idx / 24576;                 // 3*256*32
    int rem  = idx - b*24576;
    int c    = rem / 8192;                  // 256*32
    int rem2 = rem - c*8192;
    int row  = rem2 >> 5;
    int cb   = rem2 & 31;
    int ph = row >> 5, kh = row & 31;
    int pw = cb >> 2,  kw = (cb & 3) << 3;
    const float* src = img + (size_t)idx*8; // fully coalesced read
    float4 v0 = *(const float4*)src;
    float4 v1 = *(const float4*)(src + 4);
    uint4 ov; u16* tp = (u16*)&ov;
    tp[0]=f2bf(v0.x); tp[1]=f2bf(v0.y); tp[2]=f2bf(v0.z); tp[3]=f2bf(v0.w);
    tp[4]=f2bf(v1.x); tp[5]=f2bf(v1.y); tp[6]=f2bf(v1.z); tp[7]=f2bf(v1.w);
    int m = b*64 + ph*8 + pw;
    int k = c*1024 + kh*32 + kw;
    *(uint4*)(A + (size_t)m*3072 + k) = ov;
  } else {
    // cls token init
    int idx = (bx - PB_IM)*256 + t;
    int b = idx / 384, c = idx - b*384;
    X[(size_t)b*65*384 + c] = cls[c] + pos[c];
  }
}

// ---------------- LayerNorm (fp32 in, bf16 out), 1 wave per row, float2-vectorized ----------------
__global__ __launch_bounds__(256) void ln_k(const float* __restrict__ X,
                                            const float* __restrict__ w,
                                            const float* __restrict__ b,
                                            u16* __restrict__ Y){
  int row  = blockIdx.x*4 + (threadIdx.x >> 6);
  int lane = threadIdx.x & 63;
  const float2* xr = (const float2*)(X + (size_t)row*384);
  const float2* wp = (const float2*)w;
  const float2* bp = (const float2*)b;
  float2 v[3]; float s = 0.f;
  #pragma unroll
  for (int i=0;i<3;i++){ v[i] = xr[lane + i*64]; s += v[i].x + v[i].y; }
  #pragma unroll
  for (int m=1;m<64;m<<=1) s += __shfl_xor(s, m);
  float mu = s * (1.f/384.f);
  float q = 0.f;
  #pragma unroll
  for (int i=0;i<3;i++){ float dx = v[i].x-mu, dy = v[i].y-mu; q += dx*dx + dy*dy; }
  #pragma unroll
  for (int m=1;m<64;m<<=1) q += __shfl_xor(q, m);
  float rs = rsqrtf(q*(1.f/384.f) + 1e-5f);
  ushort2* yr = (ushort2*)(Y + (size_t)row*384);
  #pragma unroll
  for (int i=0;i<3;i++){
    int e2 = lane + i*64;
    float2 wv = wp[e2], bv = bp[e2];
    ushort2 o;
    o.x = f2bf((v[i].x-mu)*rs*wv.x + bv.x);
    o.y = f2bf((v[i].y-mu)*rs*wv.y + bv.y);
    yr[e2] = o;
  }
}

// ---------------- final LN on cls rows -> fp32 out [128][384], float2-vectorized ----------------
__global__ __launch_bounds__(256) void ln_final_k(const float* __restrict__ X,
                                                  const float* __restrict__ w,
                                                  const float* __restrict__ b,
                                                  float* __restrict__ out){
  int bb   = blockIdx.x*4 + (threadIdx.x >> 6);   // 128 rows
  int lane = threadIdx.x & 63;
  const float2* xr = (const float2*)(X + (size_t)bb*65*384);
  const float2* wp = (const float2*)w;
  const float2* bp = (const float2*)b;
  float2 v[3]; float s = 0.f;
  #pragma unroll
  for (int i=0;i<3;i++){ v[i] = xr[lane + i*64]; s += v[i].x + v[i].y; }
  #pragma unroll
  for (int m=1;m<64;m<<=1) s += __shfl_xor(s, m);
  float mu = s * (1.f/384.f);
  float q = 0.f;
  #pragma unroll
  for (int i=0;i<3;i++){ float dx = v[i].x-mu, dy = v[i].y-mu; q += dx*dx + dy*dy; }
  #pragma unroll
  for (int m=1;m<64;m<<=1) q += __shfl_xor(q, m);
  float rs = rsqrtf(q*(1.f/384.f) + 1e-5f);
  float2* orow = (float2*)(out + (size_t)bb*384);
  #pragma unroll
  for (int i=0;i<3;i++){
    int e2 = lane + i*64;
    float2 wv = wp[e2], bv = bp[e2];
    float2 o;
    o.x = (v[i].x-mu)*rs*wv.x + bv.x;
    o.y = (v[i].y-mu)*rs*wv.y + bv.y;
    orow[e2] = o;
  }
}

// ---------------- NT-GEMM (R5-proven): BM=64 BN=128 BK=64, 2-buffer dbuf ----------------
// MODE 0 (qkv), MODE 1 (patch embed), MODE 3 (fc1) — grids >= 384 blocks.
template<int MODE>
__global__ __launch_bounds__(256) void gemm_nt(
    const u16* __restrict__ A, const u16* __restrict__ W, int K,
    u16* __restrict__ outb, float* __restrict__ outf,
    const float* __restrict__ bias, const float* __restrict__ extra, int ldout)
{
  __shared__ u16 As[2][4096];   // [2][64][64]
  __shared__ u16 Bs[2][8192];   // [2][128][64]
  const int t    = threadIdx.x;
  const int lane = t & 63;
  const int w    = t >> 6;
  const int wr   = w >> 1, wc = w & 1;
  const int m0 = blockIdx.x * 64, n0 = blockIdx.y * 128;
  const int rs = t >> 3;
  const int cs = (((t & 7) ^ (rs & 7))) * 8;   // swizzled source col
  const u16* Ag = A + (size_t)(m0 + rs) * K + cs;
  const u16* Wg = W + (size_t)(n0 + rs) * K + cs;
  const size_t K32 = (size_t)K * 32;
  const int ln15 = lane & 15, l8 = (lane >> 4) * 8, lq = (lane >> 4) << 2;
  const int swz = (ln15 & 7) << 3;             // read-side col XOR

  f32x4 acc[2][4] = {};
  const int nk = K >> 6;
  int cur = 0;

  gld16(Ag,           &As[0][t*8]);
  gld16(Ag + K32,     &As[0][2048 + t*8]);
  gld16(Wg,           &Bs[0][t*8]);
  gld16(Wg + K32,     &Bs[0][2048 + t*8]);
  gld16(Wg + 2*K32,   &Bs[0][4096 + t*8]);
  gld16(Wg + 3*K32,   &Bs[0][6144 + t*8]);
  __syncthreads();

  for (int kt = 1; kt <= nk; kt++){
    if (kt < nk){
      const int k0 = kt << 6;
      const int nb = cur ^ 1;
      gld16(Ag + k0,         &As[nb][t*8]);
      gld16(Ag + K32 + k0,   &As[nb][2048 + t*8]);
      gld16(Wg + k0,         &Bs[nb][t*8]);
      gld16(Wg + K32 + k0,   &Bs[nb][2048 + t*8]);
      gld16(Wg + 2*K32 + k0, &Bs[nb][4096 + t*8]);
      gld16(Wg + 3*K32 + k0, &Bs[nb][6144 + t*8]);
    }
    #pragma unroll
    for (int ks = 0; ks < 2; ks++){
      const int col = (ks*32 + l8) ^ swz;
      bf16x8 af[2], bfr[4];
      #pragma unroll
      for (int mi=0; mi<2; mi++)
        af[mi] = *(const bf16x8*)(&As[cur][(wr*32 + mi*16 + ln15)*64 + col]);
      #pragma unroll
      for (int ni=0; ni<4; ni++)
        bfr[ni] = *(const bf16x8*)(&Bs[cur][(wc*64 + ni*16 + ln15)*64 + col]);
      #pragma unroll
      for (int mi=0; mi<2; mi++)
        #pragma unroll
        for (int ni=0; ni<4; ni++)
          acc[mi][ni] = __builtin_amdgcn_mfma_f32_16x16x32_bf16(af[mi], bfr[ni], acc[mi][ni], 0,0,0);
    }
    if (kt < nk) __syncthreads();
    cur ^= 1;
  }

  #pragma unroll
  for (int mi=0; mi<2; mi++){
    #pragma unroll
    for (int j=0; j<4; j++){
      const int m = m0 + wr*32 + mi*16 + lq + j;
      #pragma unroll
      for (int ni=0; ni<4; ni++){
        const int n = n0 + wc*64 + ni*16 + ln15;
        float v = acc[mi][ni][j];
        if constexpr (MODE == 0){
          outb[(size_t)m*ldout + n] = f2bf(v);
        } else if constexpr (MODE == 1){
          int bb = m >> 6, p = m & 63;
          outf[((size_t)bb*65 + 1 + p)*384 + n] = v + bias[n] + extra[(1+p)*384 + n];
        } else if constexpr (MODE == 3){
          float g = v + bias[n];
          g = 0.5f*g*(1.f + erff(g*0.70710678118f));
          outb[(size_t)m*ldout + n] = f2bf(g);
        }
      }
    }
  }
}

// ---------------- NT-GEMM BN=64 variant: BM=64 BN=64 BK=64, 2-buffer dbuf ----------------
// For small-grid GEMMs (proj/fc2): doubles block count -> ~3 blocks/CU resident.
// MODE 2: proj residual  MODE 4: fc2 residual
template<int MODE>
__global__ __launch_bounds__(256) void gemm_nt64(
    const u16* __restrict__ A, const u16* __restrict__ W, int K,
    float* __restrict__ outf, const float* __restrict__ bias,
    const float* __restrict__ extra)
{
  __shared__ u16 As[2][4096];   // [2][64][64]
  __shared__ u16 Bs[2][4096];   // [2][64][64]
  const int t    = threadIdx.x;
  const int lane = t & 63;
  const int w    = t >> 6;
  const int wr   = w >> 1, wc = w & 1;
  const int m0 = blockIdx.x * 64, n0 = blockIdx.y * 64;
  const int rs = t >> 3;
  const int cs = (((t & 7) ^ (rs & 7))) * 8;   // swizzled source col
  const u16* Ag = A + (size_t)(m0 + rs) * K + cs;
  const u16* Wg = W + (size_t)(n0 + rs) * K + cs;
  const size_t K32 = (size_t)K * 32;
  const int ln15 = lane & 15, l8 = (lane >> 4) * 8, lq = (lane >> 4) << 2;
  const int swz = (ln15 & 7) << 3;             // read-side col XOR

  f32x4 acc[2][2] = {};
  const int nk = K >> 6;
  int cur = 0;

  gld16(Ag,       &As[0][t*8]);
  gld16(Ag + K32, &As[0][2048 + t*8]);
  gld16(Wg,       &Bs[0][t*8]);
  gld16(Wg + K32, &Bs[0][2048 + t*8]);
  __syncthreads();

  for (int kt = 1; kt <= nk; kt++){
    if (kt < nk){
      const int k0 = kt << 6;
      const int nb = cur ^ 1;
      gld16(Ag + k0,       &As[nb][t*8]);
      gld16(Ag + K32 + k0, &As[nb][2048 + t*8]);
      gld16(Wg + k0,       &Bs[nb][t*8]);
      gld16(Wg + K32 + k0, &Bs[nb][2048 + t*8]);
    }
    #pragma unroll
    for (int ks = 0; ks < 2; ks++){
      const int col = (ks*32 + l8) ^ swz;
      bf16x8 af[2], bfr[2];
      #pragma unroll
      for (int mi=0; mi<2; mi++)
        af[mi] = *(const bf16x8*)(&As[cur][(wr*32 + mi*16 + ln15)*64 + col]);
      #pragma unroll
      for (int ni=0; ni<2; ni++)
        bfr[ni] = *(const bf16x8*)(&Bs[cur][(wc*32 + ni*16 + ln15)*64 + col]);
      #pragma unroll
      for (int mi=0; mi<2; mi++)
        #pragma unroll
        for (int ni=0; ni<2; ni++)
          acc[mi][ni] = __builtin_amdgcn_mfma_f32_16x16x32_bf16(af[mi], bfr[ni], acc[mi][ni], 0,0,0);
    }
    if (kt < nk) __syncthreads();
    cur ^= 1;
  }

  #pragma unroll
  for (int mi=0; mi<2; mi++){
    #pragma unroll
    for (int j=0; j<4; j++){
      const int m = m0 + wr*32 + mi*16 + lq + j;
      #pragma unroll
      for (int ni=0; ni<2; ni++){
        const int n = n0 + wc*32 + ni*16 + ln15;
        float v = acc[mi][ni][j];
        if constexpr (MODE == 2){
          outf[(size_t)m*384 + n] += v + extra[m/65]*bias[n];
        } else {
          outf[(size_t)m*384 + n] += v + bias[n];
        }
      }
    }
  }
}

// ---------------- per-(edge,head) QK^T + softmax -> Pe bf16 [512][3][80][80] ----------------
__global__ __launch_bounds__(320) void qk_k(
    const u16* __restrict__ qkv, u16* __restrict__ Pe,
    const int* __restrict__ elist, const int* __restrict__ dlist)
{
  __shared__ u16 Qs[80*128];
  __shared__ u16 Ks[80*128];
  const int ee = blockIdx.x, h = blockIdx.y;
  const int t = threadIdx.x, w = t >> 6, lane = t & 63;
  const int ln15 = lane & 15, lq = (lane >> 4) << 2, l8 = (lane >> 4) * 8;
  const int b = dlist[ee], s = elist[ee];
  const size_t qbase = (size_t)b*65*1152 + h*128;
  const size_t kbase = (size_t)s*65*1152 + 384 + h*128;

  for (int idx = t; idx < 1040; idx += 320){
    int n = idx >> 4, g = idx & 15;
    int cc = (g ^ (n & 15)) * 8;               // swizzled source col
    gld16(qkv + qbase + (size_t)n*1152 + cc, Qs + idx*8);
    gld16(qkv + kbase + (size_t)n*1152 + cc, Ks + idx*8);
  }
  __syncthreads();

  const int swz = ln15 << 3;
  u16* pe = Pe + ((size_t)ee*3 + h)*6400;
  {
    const int rt = w;   // one row-tile per wave
    f32x4 sc[5] = {};
    #pragma unroll
    for (int ks=0; ks<4; ks++){
      const int col = (ks*32 + l8) ^ swz;
      bf16x8 a = *(const bf16x8*)(Qs + (rt*16 + ln15)*128 + col);
      #pragma unroll
      for (int ct=0; ct<5; ct++){
        bf16x8 kb = *(const bf16x8*)(Ks + (ct*16 + ln15)*128 + col);
        sc[ct] = __builtin_amdgcn_mfma_f32_16x16x32_bf16(a, kb, sc[ct], 0,0,0);
      }
    }
    #pragma unroll
    for (int j=0;j<4;j++){
      const int r = rt*16 + lq + j;
      const bool c4ok = (ln15 == 0);
      float ev[5];
      float mx = -1e30f;
      #pragma unroll
      for (int ct=0; ct<5; ct++){
        float sv = sc[ct][j] * SCALE_;
        ev[ct] = sv;
        if (ct < 4 || c4ok) mx = fmaxf(mx, sv);
      }
      #pragma unroll
      for (int mm=1; mm<16; mm<<=1) mx = fmaxf(mx, __shfl_xor(mx, mm));
      float se = 0.f;
      #pragma unroll
      for (int ct=0; ct<5; ct++){
        ev[ct] = (ct < 4 || c4ok) ? expf(ev[ct]-mx) : 0.f;
        se += ev[ct];
      }
      #pragma unroll
      for (int mm=1; mm<16; mm<<=1) se += __shfl_xor(se, mm);
      const float pscale = 1.f / se;
      if (r < 65){
        #pragma unroll
        for (int ct=0; ct<5; ct++)
          pe[r*80 + ct*16 + ln15] = f2bf(ev[ct]*pscale);
      }
    }
  }
}

// ---------------- per-(dst,head) combine + PV ----------------
// Edge-gather vectorized: 6400 = 256*24 + 256; thread t owns uint4 chunks
// {t, t+256, t+512} (8 bf16 each; 80%8==0 so chunks never cross rows) plus
// scalar elem 6144+t. Same per-element accumulation order as before.
__global__ __launch_bounds__(256) void pv_k(
    const u16* __restrict__ qkv, const u16* __restrict__ Pe,
    u16* __restrict__ obar, const int* __restrict__ eoff,
    const float* __restrict__ invc)
{
  __shared__ u16 Pb[80*PVS];
  __shared__ u16 Vt[128*PVS];
  const int b = blockIdx.x, h = blockIdx.y;
  const int t = threadIdx.x, w = t >> 6, lane = t & 63;
  const int ln15 = lane & 15, lq = (lane >> 4) << 2, l8 = (lane >> 4) * 8;
  const int e0 = eoff[b], e1 = eoff[b+1];
  const float inv = invc[b];

  float a8[3][8];
  float asc = 0.f;
  #pragma unroll
  for (int i=0;i<3;i++)
    #pragma unroll
    for (int j=0;j<8;j++) a8[i][j] = 0.f;
  for (int ee = e0; ee < e1; ee++){
    const u16* pe = Pe + ((size_t)ee*3 + h)*6400;
    #pragma unroll
    for (int i=0;i<3;i++){
      uint4 v = *(const uint4*)(pe + (size_t)(t + i*256)*8);
      const u16* p = (const u16*)&v;
      #pragma unroll
      for (int j=0;j<8;j++) a8[i][j] += bf2f(p[j]);
    }
    asc += bf2f(pe[6144 + t]);
  }
  #pragma unroll
  for (int i=0;i<3;i++){
    int e = (t + i*256)*8;
    int r = e/80, c = e - r*80;
    uint4 ov; u16* op = (u16*)&ov;
    #pragma unroll
    for (int j=0;j<8;j++) op[j] = f2bf(a8[i][j]*inv);
    *(uint4*)(&Pb[r*PVS + c]) = ov;
  }
  {
    int e = 6144 + t;
    int r = e/80, c = e - r*80;
    Pb[r*PVS + c] = f2bf(asc*inv);
  }
  for (int idx = t; idx < 80*16; idx += 256)
    Pb[(idx>>4)*PVS + 80 + (idx & 15)] = 0;
  for (int idx = t; idx < 128*31; idx += 256){
    int d = idx / 31, m = 65 + (idx - d*31);
    Vt[d*PVS + m] = 0;
  }
  const size_t vbase = (size_t)b*65*1152 + 768 + h*128;
  for (int idx = t; idx < 1040; idx += 256){
    int m = idx >> 4, dc = (idx & 15)*8;
    uint4 v = *(const uint4*)(qkv + vbase + (size_t)m*1152 + dc);
    const u16* p = (const u16*)&v;
    #pragma unroll
    for (int i=0;i<8;i++) Vt[(dc+i)*PVS + m] = p[i];
  }
  __syncthreads();

  for (int ntile = w*2; ntile < w*2+2; ntile++){
    #pragma unroll
    for (int mt=0; mt<5; mt++){
      f32x4 oc = {};
      #pragma unroll
      for (int ks=0; ks<3; ks++){
        bf16x8 a  = *(const bf16x8*)(Pb + (mt*16 + ln15)*PVS + ks*32 + l8);
        bf16x8 vb = *(const bf16x8*)(Vt + (ntile*16 + ln15)*PVS + ks*32 + l8);
        oc = __builtin_amdgcn_mfma_f32_16x16x32_bf16(a, vb, oc, 0,0,0);
      }
      #pragma unroll
      for (int j=0;j<4;j++){
        int n = mt*16 + lq + j;
        if (n < 65) obar[((size_t)b*65 + n)*384 + h*128 + ntile*16 + ln15] = f2bf(oc[j]);
      }
    }
  }
}

// ---------------- launch ----------------
extern "C" void kernel_launch(void* const* d_in, const int* in_sizes, int n_in,
                              void* d_out, int out_size, void* d_ws, size_t ws_size,
                              hipStream_t stream) {
  (void)in_sizes; (void)n_in; (void)out_size; (void)ws_size;
  const float* images  = (const float*)d_in[0];
  const float* patch_w = (const float*)d_in[1];
  const float* patch_b = (const float*)d_in[2];
  const float* cls_tok = (const float*)d_in[3];
  const float* pos_emb = (const float*)d_in[4];
  const float* n1w = (const float*)d_in[5];
  const float* n1b = (const float*)d_in[6];
  const float* qkvw = (const float*)d_in[7];
  const float* projw = (const float*)d_in[8];
  const float* projb = (const float*)d_in[9];
  const float* n2w = (const float*)d_in[10];
  const float* n2b = (const float*)d_in[11];
  const float* f1w = (const float*)d_in[12];
  const float* f1b = (const float*)d_in[13];
  const float* f2w = (const float*)d_in[14];
  const float* f2b = (const float*)d_in[15];
  const float* nw  = (const float*)d_in[16];
  const float* nb  = (const float*)d_in[17];
  const int*   eidx = (const int*)d_in[18];

  char* ws = (char*)d_ws;
  float* X   = (float*)(ws + X_OFF);
  u16*   Y   = (u16*)(ws + Y_OFF);
  u16*   QKV = (u16*)(ws + QKV_OFF);
  u16*   OB  = (u16*)(ws + OBAR_OFF);
  u16*   SCR = (u16*)(ws + SCR_OFF);
  u16*   PE  = (u16*)(ws + PE_OFF);
  u16*   WB  = (u16*)(ws + WB_OFF);
  int*   ELIST = (int*)(ws + ELIST_OFF);
  int*   EOFF  = (int*)(ws + EOFF_OFF);
  float* INV   = (float*)(ws + INV_OFF);
  float* BSC   = (float*)(ws + BSC_OFF);
  int*   DLIST = (int*)(ws + DLIST_OFF);

  // merged preamble: edge_prep | weights->bf16 | im2col | cls_init (one dispatch)
  pre_k<<<PB_TOT, 256, 0, stream>>>(patch_w, qkvw, projw, f1w, f2w, WB,
                                    images, SCR,
                                    cls_tok, pos_emb, X,
                                    eidx, ELIST, EOFF, INV, BSC, DLIST);

  // patch embed GEMM: [8192,3072] x [384,3072]^T -> x tokens 1..64 (+bias+pos)
  gemm_nt<1><<<dim3(128, 3), 256, 0, stream>>>(SCR, WB + PW_E, 3072,
                                               nullptr, X, patch_b, pos_emb, 0);

  for (int d = 0; d < 6; d++){
    ln_k<<<2080, 256, 0, stream>>>(X, n1w + d*384, n1b + d*384, Y);
    gemm_nt<0><<<dim3(130, 9), 256, 0, stream>>>(Y, WB + QW_E + (size_t)d*1152*384, 384,
                                                 QKV, nullptr, nullptr, nullptr, 1152);
    qk_k<<<dim3(512, 3), 320, 0, stream>>>(QKV, PE, ELIST, DLIST);
    pv_k<<<dim3(128, 3), 256, 0, stream>>>(QKV, PE, OB, EOFF, INV);
    gemm_nt64<2><<<dim3(130, 6), 256, 0, stream>>>(OB, WB + PRW_E + (size_t)d*384*384, 384,
                                                   X, projb + d*384, BSC);
    ln_k<<<2080, 256, 0, stream>>>(X, n2w + d*384, n2b + d*384, Y);
    gemm_nt<3><<<dim3(130, 12), 256, 0, stream>>>(Y, WB + F1W_E + (size_t)d*1536*384, 384,
                                                  SCR, nullptr, f1b + d*1536, nullptr, 1536);
    gemm_nt64<4><<<dim3(130, 6), 256, 0, stream>>>(SCR, WB + F2W_E + (size_t)d*384*1536, 1536,
                                                   X, f2b + d*384, nullptr);
  }

  ln_final_k<<<32, 256, 0, stream>>>(X, nw, nb, (float*)d_out);
}

// Round 14
// 836.162 us; speedup vs baseline: 1.0386x; 1.0032x over previous
//
#include <hip/hip_runtime.h>

typedef unsigned short u16;
typedef unsigned int   u32;
typedef __attribute__((ext_vector_type(4))) float f32x4;
using bf16x8 = __attribute__((ext_vector_type(8))) __bf16;

#define AS1 __attribute__((address_space(1)))
#define AS3 __attribute__((address_space(3)))

// ---------------- constants ----------------
#define SCALE_ 0.08838834764831845f   // 128^-0.5
// sizes: B=128, E=512, C=384, N=65 tokens, HD=128, H=3, MLP_H=1536, DEPTH=6

// ---------------- workspace layout (bytes) ----------------
#define X_OFF      0ull            // fp32 [8320][384]
#define Y_OFF      12779520ull     // bf16 [8320][384]
#define QKV_OFF    19169280ull     // bf16 [8320][1152]
#define OBAR_OFF   38338560ull     // bf16 [8320][384]
#define SCR_OFF    44728320ull     // union: im2col bf16 [8192][3072] / h1 bf16 [8320][1536]
#define PE_OFF     70287360ull     // bf16 [512][3][80][80]
#define WB_OFF     95059968ull     // all weights bf16
#define ELIST_OFF  118652928ull    // int [512]  (src, sorted by dst)
#define EOFF_OFF   118654976ull    // int [129]
#define INV_OFF    118655744ull    // float [128]
#define BSC_OFF    118656256ull    // float [128]
#define DLIST_OFF  118656768ull    // int [512]  (dst per sorted edge)

// weight element offsets inside WB (contiguous regions, in order)
#define PW_E   0
#define QW_E   1179648
#define PRW_E  3833856
#define F1W_E  4718592
#define F2W_E  8257536

// cvt region boundaries in float4 units
#define R0_ 294912
#define R1_ 958464
#define R2_ 1179648
#define R3_ 2064384
#define R4_ 2949120

// pre_k block-range boundaries: edge_prep FIRST (serial block overlaps stream)
#define PB_EDGE  1
#define PB_CVT   11521   // + 11520 cvt
#define PB_IM    23809   // + 12288 im2col
#define PB_TOT   24001   // + 192 cls_init

// pv_k padded stride (elems); 208B row stride (16B-aligned: 208=16*13)
#define PVS 104

// ---------------- helpers ----------------
__device__ __forceinline__ u16 f2bf(float f){
  union { float fv; u32 u; } x; x.fv = f;
  u32 r = x.u + 0x7FFFu + ((x.u >> 16) & 1u);
  return (u16)(r >> 16);
}
__device__ __forceinline__ float bf2f(u16 u){
  union { u32 u; float fv; } x; x.u = ((u32)u) << 16;
  return x.fv;
}
__device__ __forceinline__ void gld16(const void* g, void* l){
  __builtin_amdgcn_global_load_lds((AS1 void*)g, (AS3 void*)l, 16, 0, 0);
}

// ---------------- merged preamble: edge_prep | cvt(5 tensors) | im2col | cls_init ----------------
// im2col: block = (b, c, 8-row group). Reads 8KB fully contiguous; stages bf16
// in LDS; writes 512B-contiguous segments per output row (was 64B @ 6KB stride).
__global__ __launch_bounds__(256) void pre_k(
    const float* __restrict__ patch_w, const float* __restrict__ qkvw,
    const float* __restrict__ projw, const float* __restrict__ f1w,
    const float* __restrict__ f2w, u16* __restrict__ WB,
    const float* __restrict__ img, u16* __restrict__ A,
    const float* __restrict__ cls, const float* __restrict__ pos, float* __restrict__ X,
    const int* __restrict__ ei, int* __restrict__ elist, int* __restrict__ eoff,
    float* __restrict__ inv, float* __restrict__ bsc, int* __restrict__ dlist)
{
  __shared__ int srcS[512];
  __shared__ int dstS[512];
  __shared__ int cnt[128];
  __shared__ u16 S[8][264];   // im2col staging tile (+8 pad)
  const int bx = blockIdx.x, t = threadIdx.x;

  if (bx < PB_EDGE){
    // edge bucketing (deterministic); all 256 threads reach barriers
    for (int e = t; e < 512; e += 256){ srcS[e] = ei[e]; dstS[e] = ei[512 + e]; }
    __syncthreads();
    if (t < 128){
      int c = 0;
      for (int e = 0; e < 512; e++) c += (dstS[e] == t) ? 1 : 0;
      cnt[t] = c;
    }
    __syncthreads();
    if (t < 128){
      int c = cnt[t];
      int off = 0;
      for (int b = 0; b < t; b++) off += cnt[b];
      eoff[t] = off;
      if (t == 127) eoff[128] = off + c;
      inv[t] = 1.0f / (float)(c > 1 ? c : 1);
      bsc[t] = (c > 0) ? 1.0f : 0.0f;
      int p = off;
      for (int e = 0; e < 512; e++){
        if (dstS[e] == t){ elist[p] = srcS[e]; dlist[p] = t; p++; }
      }
    }
  } else if (bx < PB_CVT){
    // fp32 -> bf16 weight convert (fully coalesced both sides)
    int i = (bx - PB_EDGE)*256 + t;
    const float* s; int rel;
    if (i < R0_)      { s = patch_w; rel = i; }
    else if (i < R1_) { s = qkvw;    rel = i - R0_; }
    else if (i < R2_) { s = projw;   rel = i - R1_; }
    else if (i < R3_) { s = f1w;     rel = i - R2_; }
    else              { s = f2w;     rel = i - R3_; }
    float4 v = ((const float4*)s)[rel];
    ushort4 o; o.x=f2bf(v.x); o.y=f2bf(v.y); o.z=f2bf(v.z); o.w=f2bf(v.w);
    ((ushort4*)WB)[i] = o;
  } else if (bx < PB_IM){
    // im2col: block ib = (b, c, g) with g = 8-row group (rows g*8..g*8+7)
    int ib = bx - PB_CVT;            // [0, 12288) = 128*3*32
    int b   = ib / 96;               // 3*32
    int rem = ib - b*96;
    int c   = rem >> 5;
    int g   = rem & 31;
    int ph  = g >> 2, kh0 = (g & 3) << 3;
    // coalesced read: 2048 consecutive floats (8 image rows)
    const float* src = img + ((size_t)(b*3 + c)*256 + g*8)*256 + t*8;
    float4 v0 = *(const float4*)src;
    float4 v1 = *(const float4*)(src + 4);
    int rl = t >> 5, col = (t & 31)*8;
    u16* sp = &S[rl][col];
    sp[0]=f2bf(v0.x); sp[1]=f2bf(v0.y); sp[2]=f2bf(v0.z); sp[3]=f2bf(v0.w);
    sp[4]=f2bf(v1.x); sp[5]=f2bf(v1.y); sp[6]=f2bf(v1.z); sp[7]=f2bf(v1.w);
    __syncthreads();
    // write: per pw, 32 threads cover (khl,kw) in k-order -> 512B contiguous
    int pw = t >> 5, j = t & 31;
    int khl = j >> 2, kw = (j & 3) << 3;
    uint4 ov = *(const uint4*)&S[khl][pw*32 + kw];
    int m = b*64 + ph*8 + pw;
    int k = c*1024 + (kh0 + khl)*32 + kw;
    *(uint4*)(A + (size_t)m*3072 + k) = ov;
  } else {
    // cls token init
    int idx = (bx - PB_IM)*256 + t;
    int b = idx / 384, c = idx - b*384;
    X[(size_t)b*65*384 + c] = cls[c] + pos[c];
  }
}

// ---------------- LayerNorm (fp32 in, bf16 out), 1 wave per row, float2-vectorized ----------------
__global__ __launch_bounds__(256) void ln_k(const float* __restrict__ X,
                                            const float* __restrict__ w,
                                            const float* __restrict__ b,
                                            u16* __restrict__ Y){
  int row  = blockIdx.x*4 + (threadIdx.x >> 6);
  int lane = threadIdx.x & 63;
  const float2* xr = (const float2*)(X + (size_t)row*384);
  const float2* wp = (const float2*)w;
  const float2* bp = (const float2*)b;
  float2 v[3]; float s = 0.f;
  #pragma unroll
  for (int i=0;i<3;i++){ v[i] = xr[lane + i*64]; s += v[i].x + v[i].y; }
  #pragma unroll
  for (int m=1;m<64;m<<=1) s += __shfl_xor(s, m);
  float mu = s * (1.f/384.f);
  float q = 0.f;
  #pragma unroll
  for (int i=0;i<3;i++){ float dx = v[i].x-mu, dy = v[i].y-mu; q += dx*dx + dy*dy; }
  #pragma unroll
  for (int m=1;m<64;m<<=1) q += __shfl_xor(q, m);
  float rs = rsqrtf(q*(1.f/384.f) + 1e-5f);
  ushort2* yr = (ushort2*)(Y + (size_t)row*384);
  #pragma unroll
  for (int i=0;i<3;i++){
    int e2 = lane + i*64;
    float2 wv = wp[e2], bv = bp[e2];
    ushort2 o;
    o.x = f2bf((v[i].x-mu)*rs*wv.x + bv.x);
    o.y = f2bf((v[i].y-mu)*rs*wv.y + bv.y);
    yr[e2] = o;
  }
}

// ---------------- final LN on cls rows -> fp32 out [128][384], float2-vectorized ----------------
__global__ __launch_bounds__(256) void ln_final_k(const float* __restrict__ X,
                                                  const float* __restrict__ w,
                                                  const float* __restrict__ b,
                                                  float* __restrict__ out){
  int bb   = blockIdx.x*4 + (threadIdx.x >> 6);   // 128 rows
  int lane = threadIdx.x & 63;
  const float2* xr = (const float2*)(X + (size_t)bb*65*384);
  const float2* wp = (const float2*)w;
  const float2* bp = (const float2*)b;
  float2 v[3]; float s = 0.f;
  #pragma unroll
  for (int i=0;i<3;i++){ v[i] = xr[lane + i*64]; s += v[i].x + v[i].y; }
  #pragma unroll
  for (int m=1;m<64;m<<=1) s += __shfl_xor(s, m);
  float mu = s * (1.f/384.f);
  float q = 0.f;
  #pragma unroll
  for (int i=0;i<3;i++){ float dx = v[i].x-mu, dy = v[i].y-mu; q += dx*dx + dy*dy; }
  #pragma unroll
  for (int m=1;m<64;m<<=1) q += __shfl_xor(q, m);
  float rs = rsqrtf(q*(1.f/384.f) + 1e-5f);
  float2* orow = (float2*)(out + (size_t)bb*384);
  #pragma unroll
  for (int i=0;i<3;i++){
    int e2 = lane + i*64;
    float2 wv = wp[e2], bv = bp[e2];
    float2 o;
    o.x = (v[i].x-mu)*rs*wv.x + bv.x;
    o.y = (v[i].y-mu)*rs*wv.y + bv.y;
    orow[e2] = o;
  }
}

// ---------------- NT-GEMM (R5-proven): BM=64 BN=128 BK=64, 2-buffer dbuf ----------------
// MODE 0 (qkv), MODE 1 (patch embed), MODE 3 (fc1) — grids >= 384 blocks.
template<int MODE>
__global__ __launch_bounds__(256) void gemm_nt(
    const u16* __restrict__ A, const u16* __restrict__ W, int K,
    u16* __restrict__ outb, float* __restrict__ outf,
    const float* __restrict__ bias, const float* __restrict__ extra, int ldout)
{
  __shared__ u16 As[2][4096];   // [2][64][64]
  __shared__ u16 Bs[2][8192];   // [2][128][64]
  const int t    = threadIdx.x;
  const int lane = t & 63;
  const int w    = t >> 6;
  const int wr   = w >> 1, wc = w & 1;
  const int m0 = blockIdx.x * 64, n0 = blockIdx.y * 128;
  const int rs = t >> 3;
  const int cs = (((t & 7) ^ (rs & 7))) * 8;   // swizzled source col
  const u16* Ag = A + (size_t)(m0 + rs) * K + cs;
  const u16* Wg = W + (size_t)(n0 + rs) * K + cs;
  const size_t K32 = (size_t)K * 32;
  const int ln15 = lane & 15, l8 = (lane >> 4) * 8, lq = (lane >> 4) << 2;
  const int swz = (ln15 & 7) << 3;             // read-side col XOR

  f32x4 acc[2][4] = {};
  const int nk = K >> 6;
  int cur = 0;

  gld16(Ag,           &As[0][t*8]);
  gld16(Ag + K32,     &As[0][2048 + t*8]);
  gld16(Wg,           &Bs[0][t*8]);
  gld16(Wg + K32,     &Bs[0][2048 + t*8]);
  gld16(Wg + 2*K32,   &Bs[0][4096 + t*8]);
  gld16(Wg + 3*K32,   &Bs[0][6144 + t*8]);
  __syncthreads();

  for (int kt = 1; kt <= nk; kt++){
    if (kt < nk){
      const int k0 = kt << 6;
      const int nb = cur ^ 1;
      gld16(Ag + k0,         &As[nb][t*8]);
      gld16(Ag + K32 + k0,   &As[nb][2048 + t*8]);
      gld16(Wg + k0,         &Bs[nb][t*8]);
      gld16(Wg + K32 + k0,   &Bs[nb][2048 + t*8]);
      gld16(Wg + 2*K32 + k0, &Bs[nb][4096 + t*8]);
      gld16(Wg + 3*K32 + k0, &Bs[nb][6144 + t*8]);
    }
    #pragma unroll
    for (int ks = 0; ks < 2; ks++){
      const int col = (ks*32 + l8) ^ swz;
      bf16x8 af[2], bfr[4];
      #pragma unroll
      for (int mi=0; mi<2; mi++)
        af[mi] = *(const bf16x8*)(&As[cur][(wr*32 + mi*16 + ln15)*64 + col]);
      #pragma unroll
      for (int ni=0; ni<4; ni++)
        bfr[ni] = *(const bf16x8*)(&Bs[cur][(wc*64 + ni*16 + ln15)*64 + col]);
      #pragma unroll
      for (int mi=0; mi<2; mi++)
        #pragma unroll
        for (int ni=0; ni<4; ni++)
          acc[mi][ni] = __builtin_amdgcn_mfma_f32_16x16x32_bf16(af[mi], bfr[ni], acc[mi][ni], 0,0,0);
    }
    if (kt < nk) __syncthreads();
    cur ^= 1;
  }

  #pragma unroll
  for (int mi=0; mi<2; mi++){
    #pragma unroll
    for (int j=0; j<4; j++){
      const int m = m0 + wr*32 + mi*16 + lq + j;
      #pragma unroll
      for (int ni=0; ni<4; ni++){
        const int n = n0 + wc*64 + ni*16 + ln15;
        float v = acc[mi][ni][j];
        if constexpr (MODE == 0){
          outb[(size_t)m*ldout + n] = f2bf(v);
        } else if constexpr (MODE == 1){
          int bb = m >> 6, p = m & 63;
          outf[((size_t)bb*65 + 1 + p)*384 + n] = v + bias[n] + extra[(1+p)*384 + n];
        } else if constexpr (MODE == 3){
          float g = v + bias[n];
          g = 0.5f*g*(1.f + erff(g*0.70710678118f));
          outb[(size_t)m*ldout + n] = f2bf(g);
        }
      }
    }
  }
}

// ---------------- NT-GEMM BN=64 variant: BM=64 BN=64 BK=64, 2-buffer dbuf ----------------
// For small-grid GEMMs (proj/fc2): doubles block count -> ~3 blocks/CU resident.
// MODE 2: proj residual  MODE 4: fc2 residual
template<int MODE>
__global__ __launch_bounds__(256) void gemm_nt64(
    const u16* __restrict__ A, const u16* __restrict__ W, int K,
    float* __restrict__ outf, const float* __restrict__ bias,
    const float* __restrict__ extra)
{
  __shared__ u16 As[2][4096];   // [2][64][64]
  __shared__ u16 Bs[2][4096];   // [2][64][64]
  const int t    = threadIdx.x;
  const int lane = t & 63;
  const int w    = t >> 6;
  const int wr   = w >> 1, wc = w & 1;
  const int m0 = blockIdx.x * 64, n0 = blockIdx.y * 64;
  const int rs = t >> 3;
  const int cs = (((t & 7) ^ (rs & 7))) * 8;   // swizzled source col
  const u16* Ag = A + (size_t)(m0 + rs) * K + cs;
  const u16* Wg = W + (size_t)(n0 + rs) * K + cs;
  const size_t K32 = (size_t)K * 32;
  const int ln15 = lane & 15, l8 = (lane >> 4) * 8, lq = (lane >> 4) << 2;
  const int swz = (ln15 & 7) << 3;             // read-side col XOR

  f32x4 acc[2][2] = {};
  const int nk = K >> 6;
  int cur = 0;

  gld16(Ag,       &As[0][t*8]);
  gld16(Ag + K32, &As[0][2048 + t*8]);
  gld16(Wg,       &Bs[0][t*8]);
  gld16(Wg + K32, &Bs[0][2048 + t*8]);
  __syncthreads();

  for (int kt = 1; kt <= nk; kt++){
    if (kt < nk){
      const int k0 = kt << 6;
      const int nb = cur ^ 1;
      gld16(Ag + k0,       &As[nb][t*8]);
      gld16(Ag + K32 + k0, &As[nb][2048 + t*8]);
      gld16(Wg + k0,       &Bs[nb][t*8]);
      gld16(Wg + K32 + k0, &Bs[nb][2048 + t*8]);
    }
    #pragma unroll
    for (int ks = 0; ks < 2; ks++){
      const int col = (ks*32 + l8) ^ swz;
      bf16x8 af[2], bfr[2];
      #pragma unroll
      for (int mi=0; mi<2; mi++)
        af[mi] = *(const bf16x8*)(&As[cur][(wr*32 + mi*16 + ln15)*64 + col]);
      #pragma unroll
      for (int ni=0; ni<2; ni++)
        bfr[ni] = *(const bf16x8*)(&Bs[cur][(wc*32 + ni*16 + ln15)*64 + col]);
      #pragma unroll
      for (int mi=0; mi<2; mi++)
        #pragma unroll
        for (int ni=0; ni<2; ni++)
          acc[mi][ni] = __builtin_amdgcn_mfma_f32_16x16x32_bf16(af[mi], bfr[ni], acc[mi][ni], 0,0,0);
    }
    if (kt < nk) __syncthreads();
    cur ^= 1;
  }

  #pragma unroll
  for (int mi=0; mi<2; mi++){
    #pragma unroll
    for (int j=0; j<4; j++){
      const int m = m0 + wr*32 + mi*16 + lq + j;
      #pragma unroll
      for (int ni=0; ni<2; ni++){
        const int n = n0 + wc*32 + ni*16 + ln15;
        float v = acc[mi][ni][j];
        if constexpr (MODE == 2){
          outf[(size_t)m*384 + n] += v + extra[m/65]*bias[n];
        } else {
          outf[(size_t)m*384 + n] += v + bias[n];
        }
      }
    }
  }
}

// ---------------- per-(edge,head) QK^T + softmax -> Pe bf16 [512][3][80][80] ----------------
__global__ __launch_bounds__(320) void qk_k(
    const u16* __restrict__ qkv, u16* __restrict__ Pe,
    const int* __restrict__ elist, const int* __restrict__ dlist)
{
  __shared__ u16 Qs[80*128];
  __shared__ u16 Ks[80*128];
  const int ee = blockIdx.x, h = blockIdx.y;
  const int t = threadIdx.x, w = t >> 6, lane = t & 63;
  const int ln15 = lane & 15, lq = (lane >> 4) << 2, l8 = (lane >> 4) * 8;
  const int b = dlist[ee], s = elist[ee];
  const size_t qbase = (size_t)b*65*1152 + h*128;
  const size_t kbase = (size_t)s*65*1152 + 384 + h*128;

  for (int idx = t; idx < 1040; idx += 320){
    int n = idx >> 4, g = idx & 15;
    int cc = (g ^ (n & 15)) * 8;               // swizzled source col
    gld16(qkv + qbase + (size_t)n*1152 + cc, Qs + idx*8);
    gld16(qkv + kbase + (size_t)n*1152 + cc, Ks + idx*8);
  }
  __syncthreads();

  const int swz = ln15 << 3;
  u16* pe = Pe + ((size_t)ee*3 + h)*6400;
  {
    const int rt = w;   // one row-tile per wave
    f32x4 sc[5] = {};
    #pragma unroll
    for (int ks=0; ks<4; ks++){
      const int col = (ks*32 + l8) ^ swz;
      bf16x8 a = *(const bf16x8*)(Qs + (rt*16 + ln15)*128 + col);
      #pragma unroll
      for (int ct=0; ct<5; ct++){
        bf16x8 kb = *(const bf16x8*)(Ks + (ct*16 + ln15)*128 + col);
        sc[ct] = __builtin_amdgcn_mfma_f32_16x16x32_bf16(a, kb, sc[ct], 0,0,0);
      }
    }
    #pragma unroll
    for (int j=0;j<4;j++){
      const int r = rt*16 + lq + j;
      const bool c4ok = (ln15 == 0);
      float ev[5];
      float mx = -1e30f;
      #pragma unroll
      for (int ct=0; ct<5; ct++){
        float sv = sc[ct][j] * SCALE_;
        ev[ct] = sv;
        if (ct < 4 || c4ok) mx = fmaxf(mx, sv);
      }
      #pragma unroll
      for (int mm=1; mm<16; mm<<=1) mx = fmaxf(mx, __shfl_xor(mx, mm));
      float se = 0.f;
      #pragma unroll
      for (int ct=0; ct<5; ct++){
        ev[ct] = (ct < 4 || c4ok) ? expf(ev[ct]-mx) : 0.f;
        se += ev[ct];
      }
      #pragma unroll
      for (int mm=1; mm<16; mm<<=1) se += __shfl_xor(se, mm);
      const float pscale = 1.f / se;
      if (r < 65){
        #pragma unroll
        for (int ct=0; ct<5; ct++)
          pe[r*80 + ct*16 + ln15] = f2bf(ev[ct]*pscale);
      }
    }
  }
}

// ---------------- per-(dst,head) combine + PV ----------------
// Edge-gather vectorized: 6400 = 256*24 + 256; thread t owns uint4 chunks
// {t, t+256, t+512} (8 bf16 each; 80%8==0 so chunks never cross rows) plus
// scalar elem 6144+t. Same per-element accumulation order as before.
__global__ __launch_bounds__(256) void pv_k(
    const u16* __restrict__ qkv, const u16* __restrict__ Pe,
    u16* __restrict__ obar, const int* __restrict__ eoff,
    const float* __restrict__ invc)
{
  __shared__ u16 Pb[80*PVS];
  __shared__ u16 Vt[128*PVS];
  const int b = blockIdx.x, h = blockIdx.y;
  const int t = threadIdx.x, w = t >> 6, lane = t & 63;
  const int ln15 = lane & 15, lq = (lane >> 4) << 2, l8 = (lane >> 4) * 8;
  const int e0 = eoff[b], e1 = eoff[b+1];
  const float inv = invc[b];

  float a8[3][8];
  float asc = 0.f;
  #pragma unroll
  for (int i=0;i<3;i++)
    #pragma unroll
    for (int j=0;j<8;j++) a8[i][j] = 0.f;
  for (int ee = e0; ee < e1; ee++){
    const u16* pe = Pe + ((size_t)ee*3 + h)*6400;
    #pragma unroll
    for (int i=0;i<3;i++){
      uint4 v = *(const uint4*)(pe + (size_t)(t + i*256)*8);
      const u16* p = (const u16*)&v;
      #pragma unroll
      for (int j=0;j<8;j++) a8[i][j] += bf2f(p[j]);
    }
    asc += bf2f(pe[6144 + t]);
  }
  #pragma unroll
  for (int i=0;i<3;i++){
    int e = (t + i*256)*8;
    int r = e/80, c = e - r*80;
    uint4 ov; u16* op = (u16*)&ov;
    #pragma unroll
    for (int j=0;j<8;j++) op[j] = f2bf(a8[i][j]*inv);
    *(uint4*)(&Pb[r*PVS + c]) = ov;
  }
  {
    int e = 6144 + t;
    int r = e/80, c = e - r*80;
    Pb[r*PVS + c] = f2bf(asc*inv);
  }
  for (int idx = t; idx < 80*16; idx += 256)
    Pb[(idx>>4)*PVS + 80 + (idx & 15)] = 0;
  for (int idx = t; idx < 128*31; idx += 256){
    int d = idx / 31, m = 65 + (idx - d*31);
    Vt[d*PVS + m] = 0;
  }
  const size_t vbase = (size_t)b*65*1152 + 768 + h*128;
  for (int idx = t; idx < 1040; idx += 256){
    int m = idx >> 4, dc = (idx & 15)*8;
    uint4 v = *(const uint4*)(qkv + vbase + (size_t)m*1152 + dc);
    const u16* p = (const u16*)&v;
    #pragma unroll
    for (int i=0;i<8;i++) Vt[(dc+i)*PVS + m] = p[i];
  }
  __syncthreads();

  for (int ntile = w*2; ntile < w*2+2; ntile++){
    #pragma unroll
    for (int mt=0; mt<5; mt++){
      f32x4 oc = {};
      #pragma unroll
      for (int ks=0; ks<3; ks++){
        bf16x8 a  = *(const bf16x8*)(Pb + (mt*16 + ln15)*PVS + ks*32 + l8);
        bf16x8 vb = *(const bf16x8*)(Vt + (ntile*16 + ln15)*PVS + ks*32 + l8);
        oc = __builtin_amdgcn_mfma_f32_16x16x32_bf16(a, vb, oc, 0,0,0);
      }
      #pragma unroll
      for (int j=0;j<4;j++){
        int n = mt*16 + lq + j;
        if (n < 65) obar[((size_t)b*65 + n)*384 + h*128 + ntile*16 + ln15] = f2bf(oc[j]);
      }
    }
  }
}

// ---------------- launch ----------------
extern "C" void kernel_launch(void* const* d_in, const int* in_sizes, int n_in,
                              void* d_out, int out_size, void* d_ws, size_t ws_size,
                              hipStream_t stream) {
  (void)in_sizes; (void)n_in; (void)out_size; (void)ws_size;
  const float* images  = (const float*)d_in[0];
  const float* patch_w = (const float*)d_in[1];
  const float* patch_b = (const float*)d_in[2];
  const float* cls_tok = (const float*)d_in[3];
  const float* pos_emb = (const float*)d_in[4];
  const float* n1w = (const float*)d_in[5];
  const float* n1b = (const float*)d_in[6];
  const float* qkvw = (const float*)d_in[7];
  const float* projw = (const float*)d_in[8];
  const float* projb = (const float*)d_in[9];
  const float* n2w = (const float*)d_in[10];
  const float* n2b = (const float*)d_in[11];
  const float* f1w = (const float*)d_in[12];
  const float* f1b = (const float*)d_in[13];
  const float* f2w = (const float*)d_in[14];
  const float* f2b = (const float*)d_in[15];
  const float* nw  = (const float*)d_in[16];
  const float* nb  = (const float*)d_in[17];
  const int*   eidx = (const int*)d_in[18];

  char* ws = (char*)d_ws;
  float* X   = (float*)(ws + X_OFF);
  u16*   Y   = (u16*)(ws + Y_OFF);
  u16*   QKV = (u16*)(ws + QKV_OFF);
  u16*   OB  = (u16*)(ws + OBAR_OFF);
  u16*   SCR = (u16*)(ws + SCR_OFF);
  u16*   PE  = (u16*)(ws + PE_OFF);
  u16*   WB  = (u16*)(ws + WB_OFF);
  int*   ELIST = (int*)(ws + ELIST_OFF);
  int*   EOFF  = (int*)(ws + EOFF_OFF);
  float* INV   = (float*)(ws + INV_OFF);
  float* BSC   = (float*)(ws + BSC_OFF);
  int*   DLIST = (int*)(ws + DLIST_OFF);

  // merged preamble: edge_prep | weights->bf16 | im2col | cls_init (one dispatch)
  pre_k<<<PB_TOT, 256, 0, stream>>>(patch_w, qkvw, projw, f1w, f2w, WB,
                                    images, SCR,
                                    cls_tok, pos_emb, X,
                                    eidx, ELIST, EOFF, INV, BSC, DLIST);

  // patch embed GEMM: [8192,3072] x [384,3072]^T -> x tokens 1..64 (+bias+pos)
  gemm_nt<1><<<dim3(128, 3), 256, 0, stream>>>(SCR, WB + PW_E, 3072,
                                               nullptr, X, patch_b, pos_emb, 0);

  for (int d = 0; d < 6; d++){
    ln_k<<<2080, 256, 0, stream>>>(X, n1w + d*384, n1b + d*384, Y);
    gemm_nt<0><<<dim3(130, 9), 256, 0, stream>>>(Y, WB + QW_E + (size_t)d*1152*384, 384,
                                                 QKV, nullptr, nullptr, nullptr, 1152);
    qk_k<<<dim3(512, 3), 320, 0, stream>>>(QKV, PE, ELIST, DLIST);
    pv_k<<<dim3(128, 3), 256, 0, stream>>>(QKV, PE, OB, EOFF, INV);
    gemm_nt64<2><<<dim3(130, 6), 256, 0, stream>>>(OB, WB + PRW_E + (size_t)d*384*384, 384,
                                                   X, projb + d*384, BSC);
    ln_k<<<2080, 256, 0, stream>>>(X, n2w + d*384, n2b + d*384, Y);
    gemm_nt<3><<<dim3(130, 12), 256, 0, stream>>>(Y, WB + F1W_E + (size_t)d*1536*384, 384,
                                                  SCR, nullptr, f1b + d*1536, nullptr, 1536);
    gemm_nt64<4><<<dim3(130, 6), 256, 0, stream>>>(SCR, WB + F2W_E + (size_t)d*384*1536, 1536,
                                                   X, f2b + d*384, nullptr);
  }

  ln_final_k<<<32, 256, 0, stream>>>(X, nw, nb, (float*)d_out);
}